// Round 1
// baseline (406.591 us; speedup 1.0000x reference)
//
#include <hip/hip_runtime.h>
#include <hip/hip_bf16.h>

typedef unsigned short u16;
typedef unsigned int u32;
typedef __attribute__((ext_vector_type(8))) short short8;
typedef __attribute__((ext_vector_type(4))) float f32x4;
typedef __attribute__((ext_vector_type(4))) u16 u16x4;

#define DEV __device__ __forceinline__

DEV u16 f2bf(float f) {
    union { float f; u32 u; } v; v.f = f;
    u32 r = v.u;
    u32 lsb = (r >> 16) & 1u;
    r += 0x7fffu + lsb;
    return (u16)(r >> 16);
}

DEV void gload_lds16(const u16* g, u16* l) {
    __builtin_amdgcn_global_load_lds(
        (const __attribute__((address_space(1))) u32*)(const void*)g,
        (__attribute__((address_space(3))) u32*)(void*)l,
        16, 0, 0);
}

// ---------------- transpose + cast: in[R][C] fp32 -> out[C][R] bf16 ----------------
__global__ void transpose_cast(const float* __restrict__ in, u16* __restrict__ out,
                               int R, int C) {
    __shared__ float tile[32][33];
    int c0 = blockIdx.x * 32, r0 = blockIdx.y * 32;
    int tx = threadIdx.x, ty = threadIdx.y; // 32 x 8
#pragma unroll
    for (int i = 0; i < 4; i++)
        tile[ty * 4 + i][tx] = in[(size_t)(r0 + ty * 4 + i) * C + c0 + tx];
    __syncthreads();
#pragma unroll
    for (int i = 0; i < 4; i++)
        out[(size_t)(c0 + ty * 4 + i) * R + r0 + tx] = f2bf(tile[tx][ty * 4 + i]);
}

// ---------------- RMSNorm + cast to bf16: x[4096][2048] -> xn ----------------
__global__ void rmsnorm_cast(const float* __restrict__ x, const float* __restrict__ gamma,
                             u16* __restrict__ xn) {
    int row = blockIdx.x;
    int t = threadIdx.x; // 256
    const float4* xr = (const float4*)(x + (size_t)row * 2048);
    float4 a = xr[t];
    float4 b = xr[256 + t];
    float ss = a.x * a.x + a.y * a.y + a.z * a.z + a.w * a.w +
               b.x * b.x + b.y * b.y + b.z * b.z + b.w * b.w;
#pragma unroll
    for (int off = 32; off; off >>= 1) ss += __shfl_xor(ss, off);
    __shared__ float red[4];
    if ((t & 63) == 0) red[t >> 6] = ss;
    __syncthreads();
    float tot = red[0] + red[1] + red[2] + red[3];
    float n = sqrtf(tot);
    float inv = 45.254833995939045f / fmaxf(n, 1e-12f); // sqrt(2048)/max(n,eps)
    const float4* gr = (const float4*)gamma;
    float4 g0 = gr[t], g1 = gr[256 + t];
    u16x4 o0 = { f2bf(a.x * inv * (g0.x + 1.f)), f2bf(a.y * inv * (g0.y + 1.f)),
                 f2bf(a.z * inv * (g0.z + 1.f)), f2bf(a.w * inv * (g0.w + 1.f)) };
    u16x4 o1 = { f2bf(b.x * inv * (g1.x + 1.f)), f2bf(b.y * inv * (g1.y + 1.f)),
                 f2bf(b.z * inv * (g1.z + 1.f)), f2bf(b.w * inv * (g1.w + 1.f)) };
    u16x4* xo = (u16x4*)(xn + (size_t)row * 2048);
    xo[t] = o0;
    xo[256 + t] = o1;
}

// ---------------- GEMM: C[M,N] = A[M,K] @ BT[N,K]^T (bf16 in, fp32 acc) ----------------
// EPI 0: scatter to q (scaled 0.125), k as [b,h,n,d]; v transposed as [b,h,d,n]
// EPI 1: write fp32 to Cout
template <int EPI>
__global__ __launch_bounds__(256, 2) void gemm_bt(
    const u16* __restrict__ A, const u16* __restrict__ BT,
    int M, int N, int K,
    float* __restrict__ Cout,
    u16* __restrict__ qb, u16* __restrict__ kb, u16* __restrict__ vT) {
    // LDS layout: [g][row][8] bf16, g = k-chunk (8 elems), row = tile row (128)
    __shared__ __align__(16) u16 As[4096];
    __shared__ __align__(16) u16 Bs[4096];
    int t = threadIdx.x;
    int lane = t & 63, wave = t >> 6;
    int g = lane >> 4, r = lane & 15;
    int brow = blockIdx.y * 128, bcol = blockIdx.x * 128;
    int wr = (wave >> 1) * 64, wc = (wave & 1) * 64;

    f32x4 acc[4][4] = {};

    // staging: call c covers 16B-chunks [c*256, c*256+256); chunk = g*128 + row
    int g0 = t >> 7, row0 = t & 127;
    int g1 = (256 + t) >> 7, row1 = t & 127;
    const u16* Arow0 = A + (size_t)(brow + row0) * K + g0 * 8;
    const u16* Arow1 = A + (size_t)(brow + row1) * K + g1 * 8;
    const u16* Brow0 = BT + (size_t)(bcol + row0) * K + g0 * 8;
    const u16* Brow1 = BT + (size_t)(bcol + row1) * K + g1 * 8;
    u16* lA0 = As + wave * 512;
    u16* lA1 = As + 2048 + wave * 512;
    u16* lB0 = Bs + wave * 512;
    u16* lB1 = Bs + 2048 + wave * 512;

    for (int k0 = 0; k0 < K; k0 += 32) {
        __syncthreads();
        gload_lds16(Arow0 + k0, lA0);
        gload_lds16(Arow1 + k0, lA1);
        gload_lds16(Brow0 + k0, lB0);
        gload_lds16(Brow1 + k0, lB1);
        __syncthreads();
        short8 af[4], bf[4];
#pragma unroll
        for (int m = 0; m < 4; m++)
            af[m] = *(const short8*)&As[(size_t)(g * 128 + wr + m * 16 + r) * 8];
#pragma unroll
        for (int n = 0; n < 4; n++)
            bf[n] = *(const short8*)&Bs[(size_t)(g * 128 + wc + n * 16 + r) * 8];
#pragma unroll
        for (int m = 0; m < 4; m++)
#pragma unroll
            for (int n = 0; n < 4; n++)
                acc[m][n] = __builtin_amdgcn_mfma_f32_16x16x32_bf16(af[m], bf[n], acc[m][n], 0, 0, 0);
    }

    if (EPI == 0) {
#pragma unroll
        for (int m = 0; m < 4; m++)
#pragma unroll
            for (int n = 0; n < 4; n++) {
                int cb = bcol + wc + n * 16 + r; // global col in [0,3072)
                int which = cb >> 10;
                int hd = cb & 1023;
                int h = hd >> 6, d = hd & 63;
#pragma unroll
                for (int j = 0; j < 4; j++) {
                    int rr = brow + wr + m * 16 + 4 * g + j; // global row
                    int b = rr >> 11, nn = rr & 2047;
                    float v = acc[m][n][j];
                    size_t bh = (size_t)(b * 16 + h);
                    if (which == 0)      qb[(bh * 2048 + nn) * 64 + d] = f2bf(v * 0.125f);
                    else if (which == 1) kb[(bh * 2048 + nn) * 64 + d] = f2bf(v);
                    else                 vT[(bh * 64 + d) * 2048 + nn] = f2bf(v);
                }
            }
    } else {
#pragma unroll
        for (int m = 0; m < 4; m++)
#pragma unroll
            for (int n = 0; n < 4; n++) {
                int cb = bcol + wc + n * 16 + r;
#pragma unroll
                for (int j = 0; j < 4; j++) {
                    int rr = brow + wr + m * 16 + 4 * g + j;
                    Cout[(size_t)rr * N + cb] = acc[m][n][j];
                }
            }
    }
}

// ---------------- flash attention with softcap + transfusion mask ----------------
// q,k: [b][h][n][64] bf16 (q pre-scaled), vT: [b][h][64][n] bf16
// out: attn_out [b*2048+n][h*64+d] bf16
__global__ __launch_bounds__(256, 4) void flash_attn(
    const u16* __restrict__ q, const u16* __restrict__ kk, const u16* __restrict__ vT,
    const int* __restrict__ mods, u16* __restrict__ attn_out) {
    __shared__ __align__(16) u16 Plds[4][16][40]; // per-wave [q=16][kv stride 40]
    int qs = blockIdx.x * 64;
    int h = blockIdx.y, b = blockIdx.z;
    int t = threadIdx.x, lane = t & 63, wave = t >> 6;
    int g = lane >> 4, r = lane & 15;
    int bh = b * 16 + h;
    int qbase = qs + wave * 16;

    int off0 = mods[b * 6 + 1], end0 = off0 + mods[b * 6 + 2];
    int off1 = mods[b * 6 + 4], end1 = off1 + mods[b * 6 + 5];

    const u16* Qp = q + ((size_t)bh * 2048 + qbase) * 64;
    short8 qf0 = *(const short8*)(Qp + (size_t)r * 64 + 8 * g);
    short8 qf1 = *(const short8*)(Qp + (size_t)r * 64 + 32 + 8 * g);

    int jl = qbase + 16;
    if (qbase + 15 >= off0) jl = max(jl, end0);
    if (qbase + 15 >= off1) jl = max(jl, end1);

    f32x4 ot[4] = {};
    float mrow = -1e30f, lrow = 0.f;
    int iq = qbase + r;

    const u16* Kp = kk + (size_t)bh * 2048 * 64;
    const u16* Vp = vT + (size_t)bh * 64 * 2048;
    u16* Pw = &Plds[wave][0][0];

    for (int jb = 0; jb < jl; jb += 32) {
        f32x4 st[2];
#pragma unroll
        for (int tt = 0; tt < 2; tt++) {
            const u16* Kr = Kp + (size_t)(jb + 16 * tt + r) * 64 + 8 * g;
            short8 kf0 = *(const short8*)Kr;
            short8 kf1 = *(const short8*)(Kr + 32);
            f32x4 z = {};
            z = __builtin_amdgcn_mfma_f32_16x16x32_bf16(kf0, qf0, z, 0, 0, 0);
            z = __builtin_amdgcn_mfma_f32_16x16x32_bf16(kf1, qf1, z, 0, 0, 0);
            st[tt] = z;
        }
        float s[8];
        float pmax = -1e30f;
#pragma unroll
        for (int tt = 0; tt < 2; tt++)
#pragma unroll
            for (int j = 0; j < 4; j++) {
                int kv = jb + 16 * tt + 4 * g + j;
                float x = st[tt][j];
                float xx = x * 0.02f;
                float e = __expf(-2.f * fabsf(xx));
                float th = (1.f - e) / (1.f + e);
                x = 50.f * copysignf(th, xx);
                bool ok = (kv <= iq) || ((iq >= off0) && (kv < end0)) || ((iq >= off1) && (kv < end1));
                x = ok ? x : -1e30f;
                s[tt * 4 + j] = x;
                pmax = fmaxf(pmax, x);
            }
        pmax = fmaxf(pmax, __shfl_xor(pmax, 16));
        pmax = fmaxf(pmax, __shfl_xor(pmax, 32));
        float mnew = fmaxf(mrow, pmax);
        float alpha = __expf(mrow - mnew);
        float psum = 0.f;
        u32 pk[4];
#pragma unroll
        for (int i = 0; i < 8; i += 2) {
            float p0 = __expf(s[i] - mnew);
            float p1 = __expf(s[i + 1] - mnew);
            psum += p0 + p1;
            pk[i >> 1] = (u32)f2bf(p0) | ((u32)f2bf(p1) << 16);
        }
        psum += __shfl_xor(psum, 16);
        psum += __shfl_xor(psum, 32);
        lrow = lrow * alpha + psum;
        mrow = mnew;
#pragma unroll
        for (int dt = 0; dt < 4; dt++) ot[dt] *= alpha;
        // P[q=r][kv] -> LDS (packed pairs)
#pragma unroll
        for (int tt = 0; tt < 2; tt++)
#pragma unroll
            for (int jp = 0; jp < 2; jp++)
                *(u32*)&Pw[r * 40 + 16 * tt + 4 * g + 2 * jp] = pk[tt * 2 + jp];
        short8 pf = *(const short8*)&Pw[r * 40 + 8 * g];
#pragma unroll
        for (int dt = 0; dt < 4; dt++) {
            const u16* Vr = Vp + (size_t)(dt * 16 + r) * 2048 + jb + 8 * g;
            short8 vf = *(const short8*)Vr;
            ot[dt] = __builtin_amdgcn_mfma_f32_16x16x32_bf16(vf, pf, ot[dt], 0, 0, 0);
        }
    }
    float inv = 1.f / lrow;
    u16* Op = attn_out + ((size_t)(b * 2048 + qbase + r)) * 1024 + h * 64;
#pragma unroll
    for (int dt = 0; dt < 4; dt++) {
        u16x4 o = { f2bf(ot[dt][0] * inv), f2bf(ot[dt][1] * inv),
                    f2bf(ot[dt][2] * inv), f2bf(ot[dt][3] * inv) };
        *(u16x4*)(Op + dt * 16 + 4 * g) = o;
    }
}

extern "C" void kernel_launch(void* const* d_in, const int* in_sizes, int n_in,
                              void* d_out, int out_size, void* d_ws, size_t ws_size,
                              hipStream_t stream) {
    const float* x = (const float*)d_in[0];
    const float* gamma = (const float*)d_in[1];
    const float* w_qkv = (const float*)d_in[2];
    const float* w_out = (const float*)d_in[3];
    const int* mods = (const int*)d_in[4];
    float* out = (float*)d_out;

    u16* ws = (u16*)d_ws;
    u16* xn    = ws;                 // 4096*2048
    u16* wqkvT = ws + 8388608;       // 3072*2048
    u16* woutT = ws + 14680064;      // 2048*1024
    u16* qb    = ws + 16777216;      // 2*16*2048*64
    u16* kb    = ws + 20971520;
    u16* vT    = ws + 25165824;
    u16* ao    = ws + 29360128;      // 4096*1024

    transpose_cast<<<dim3(96, 64), dim3(32, 8), 0, stream>>>(w_qkv, wqkvT, 2048, 3072);
    transpose_cast<<<dim3(64, 32), dim3(32, 8), 0, stream>>>(w_out, woutT, 1024, 2048);
    rmsnorm_cast<<<dim3(4096), dim3(256), 0, stream>>>(x, gamma, xn);
    gemm_bt<0><<<dim3(24, 32), dim3(256), 0, stream>>>(xn, wqkvT, 4096, 3072, 2048,
                                                       nullptr, qb, kb, vT);
    flash_attn<<<dim3(32, 16, 2), dim3(256), 0, stream>>>(qb, kb, vT, mods, ao);
    gemm_bt<1><<<dim3(16, 32), dim3(256), 0, stream>>>(ao, woutT, 4096, 2048, 1024,
                                                       out, nullptr, nullptr, nullptr);
}

// Round 2
// 403.220 us; speedup vs baseline: 1.0084x; 1.0084x over previous
//
#include <hip/hip_runtime.h>
#include <hip/hip_bf16.h>

typedef unsigned short u16;
typedef unsigned int u32;
typedef __attribute__((ext_vector_type(8))) short short8;
typedef __attribute__((ext_vector_type(4))) float f32x4;
typedef __attribute__((ext_vector_type(4))) u16 u16x4;

#define DEV __device__ __forceinline__

DEV u16 f2bf(float f) {
    union { float f; u32 u; } v; v.f = f;
    u32 r = v.u;
    u32 lsb = (r >> 16) & 1u;
    r += 0x7fffu + lsb;
    return (u16)(r >> 16);
}

DEV void gload_lds16(const u16* g, u16* l) {
    __builtin_amdgcn_global_load_lds(
        (const __attribute__((address_space(1))) u32*)(const void*)g,
        (__attribute__((address_space(3))) u32*)(void*)l,
        16, 0, 0);
}

// ---------------- transpose + cast: in[R][C] fp32 -> out[C][R] bf16 ----------------
__global__ void transpose_cast(const float* __restrict__ in, u16* __restrict__ out,
                               int R, int C) {
    __shared__ float tile[32][33];
    int c0 = blockIdx.x * 32, r0 = blockIdx.y * 32;
    int tx = threadIdx.x, ty = threadIdx.y; // 32 x 8
#pragma unroll
    for (int i = 0; i < 4; i++)
        tile[ty * 4 + i][tx] = in[(size_t)(r0 + ty * 4 + i) * C + c0 + tx];
    __syncthreads();
#pragma unroll
    for (int i = 0; i < 4; i++)
        out[(size_t)(c0 + ty * 4 + i) * R + r0 + tx] = f2bf(tile[tx][ty * 4 + i]);
}

// ---------------- RMSNorm + cast to bf16: x[4096][2048] -> xn ----------------
__global__ void rmsnorm_cast(const float* __restrict__ x, const float* __restrict__ gamma,
                             u16* __restrict__ xn) {
    int row = blockIdx.x;
    int t = threadIdx.x; // 256
    const float4* xr = (const float4*)(x + (size_t)row * 2048);
    float4 a = xr[t];
    float4 b = xr[256 + t];
    float ss = a.x * a.x + a.y * a.y + a.z * a.z + a.w * a.w +
               b.x * b.x + b.y * b.y + b.z * b.z + b.w * b.w;
#pragma unroll
    for (int off = 32; off; off >>= 1) ss += __shfl_xor(ss, off);
    __shared__ float red[4];
    if ((t & 63) == 0) red[t >> 6] = ss;
    __syncthreads();
    float tot = red[0] + red[1] + red[2] + red[3];
    float n = sqrtf(tot);
    float inv = 45.254833995939045f / fmaxf(n, 1e-12f); // sqrt(2048)/max(n,eps)
    const float4* gr = (const float4*)gamma;
    float4 g0 = gr[t], g1 = gr[256 + t];
    u16x4 o0 = { f2bf(a.x * inv * (g0.x + 1.f)), f2bf(a.y * inv * (g0.y + 1.f)),
                 f2bf(a.z * inv * (g0.z + 1.f)), f2bf(a.w * inv * (g0.w + 1.f)) };
    u16x4 o1 = { f2bf(b.x * inv * (g1.x + 1.f)), f2bf(b.y * inv * (g1.y + 1.f)),
                 f2bf(b.z * inv * (g1.z + 1.f)), f2bf(b.w * inv * (g1.w + 1.f)) };
    u16x4* xo = (u16x4*)(xn + (size_t)row * 2048);
    xo[t] = o0;
    xo[256 + t] = o1;
}

// ---------------- GEMM: C[M,N] = A[M,K] @ BT[N,K]^T (bf16 in, fp32 acc) ----------------
template <int EPI>
__global__ __launch_bounds__(256, 2) void gemm_bt(
    const u16* __restrict__ A, const u16* __restrict__ BT,
    int M, int N, int K,
    float* __restrict__ Cout,
    u16* __restrict__ qb, u16* __restrict__ kb, u16* __restrict__ vT) {
    __shared__ __align__(16) u16 As[4096];
    __shared__ __align__(16) u16 Bs[4096];
    int t = threadIdx.x;
    int lane = t & 63, wave = t >> 6;
    int g = lane >> 4, r = lane & 15;
    int brow = blockIdx.y * 128, bcol = blockIdx.x * 128;
    int wr = (wave >> 1) * 64, wc = (wave & 1) * 64;

    f32x4 acc[4][4] = {};

    int g0 = t >> 7, row0 = t & 127;
    int g1 = (256 + t) >> 7, row1 = t & 127;
    const u16* Arow0 = A + (size_t)(brow + row0) * K + g0 * 8;
    const u16* Arow1 = A + (size_t)(brow + row1) * K + g1 * 8;
    const u16* Brow0 = BT + (size_t)(bcol + row0) * K + g0 * 8;
    const u16* Brow1 = BT + (size_t)(bcol + row1) * K + g1 * 8;
    u16* lA0 = As + wave * 512;
    u16* lA1 = As + 2048 + wave * 512;
    u16* lB0 = Bs + wave * 512;
    u16* lB1 = Bs + 2048 + wave * 512;

    for (int k0 = 0; k0 < K; k0 += 32) {
        __syncthreads();
        gload_lds16(Arow0 + k0, lA0);
        gload_lds16(Arow1 + k0, lA1);
        gload_lds16(Brow0 + k0, lB0);
        gload_lds16(Brow1 + k0, lB1);
        __syncthreads();
        short8 af[4], bf[4];
#pragma unroll
        for (int m = 0; m < 4; m++)
            af[m] = *(const short8*)&As[(size_t)(g * 128 + wr + m * 16 + r) * 8];
#pragma unroll
        for (int n = 0; n < 4; n++)
            bf[n] = *(const short8*)&Bs[(size_t)(g * 128 + wc + n * 16 + r) * 8];
#pragma unroll
        for (int m = 0; m < 4; m++)
#pragma unroll
            for (int n = 0; n < 4; n++)
                acc[m][n] = __builtin_amdgcn_mfma_f32_16x16x32_bf16(af[m], bf[n], acc[m][n], 0, 0, 0);
    }

    if (EPI == 0) {
#pragma unroll
        for (int m = 0; m < 4; m++)
#pragma unroll
            for (int n = 0; n < 4; n++) {
                int cb = bcol + wc + n * 16 + r;
                int which = cb >> 10;
                int hd = cb & 1023;
                int h = hd >> 6, d = hd & 63;
#pragma unroll
                for (int j = 0; j < 4; j++) {
                    int rr = brow + wr + m * 16 + 4 * g + j;
                    int b = rr >> 11, nn = rr & 2047;
                    float v = acc[m][n][j];
                    size_t bh = (size_t)(b * 16 + h);
                    if (which == 0)      qb[(bh * 2048 + nn) * 64 + d] = f2bf(v * 0.125f);
                    else if (which == 1) kb[(bh * 2048 + nn) * 64 + d] = f2bf(v);
                    else                 vT[(bh * 64 + d) * 2048 + nn] = f2bf(v);
                }
            }
    } else {
#pragma unroll
        for (int m = 0; m < 4; m++)
#pragma unroll
            for (int n = 0; n < 4; n++) {
                int cb = bcol + wc + n * 16 + r;
#pragma unroll
                for (int j = 0; j < 4; j++) {
                    int rr = brow + wr + m * 16 + 4 * g + j;
                    Cout[(size_t)rr * N + cb] = acc[m][n][j];
                }
            }
    }
}

// ---------------- flash attention v2: no-running-max softcap softmax ----------------
// softcap bounds s to [-50,50] => fixed max works: p = exp(s) always representable.
// mask = union of prefixes => single compare kv < rowlim.
// tanh(x/50)*50 ~ x*(1 + x2*(c3 + x2*c5)) (5th order, |err|<1e-3 for |x|<=10)
// q,k: [b][h][n][64] bf16 (q pre-scaled), vT: [b][h][64][n] bf16
__global__ __launch_bounds__(256, 4) void flash_attn(
    const u16* __restrict__ q, const u16* __restrict__ kk, const u16* __restrict__ vT,
    const int* __restrict__ mods, u16* __restrict__ attn_out) {
    __shared__ __align__(16) u16 Plds[4][16][72]; // per-wave [q=16][kv stride 72]
    int t = threadIdx.x, lane = t & 63, wave = t >> 6;
    int g = lane >> 4, r = lane & 15;
    int h = blockIdx.y, b = blockIdx.z;
    // descending work order: longest q-tiles dispatched first
    int unit = (gridDim.x - 1 - blockIdx.x) * 4 + wave; // 0..127
    int qbase = unit * 16;
    int bh = b * 16 + h;

    int off0 = mods[b * 6 + 1], end0 = off0 + mods[b * 6 + 2];
    int off1 = mods[b * 6 + 4], end1 = off1 + mods[b * 6 + 5];

    const u16* Qp = q + ((size_t)bh * 2048 + qbase) * 64;
    short8 qf0 = *(const short8*)(Qp + (size_t)r * 64 + 8 * g);
    short8 qf1 = *(const short8*)(Qp + (size_t)r * 64 + 32 + 8 * g);

    int iq = qbase + r;
    int lim0 = (iq >= off0) ? end0 : 0;
    int lim1 = (iq >= off1) ? end1 : 0;
    int rowlim = max(iq + 1, max(lim0, lim1));

    int jl = qbase + 16;
    if (qbase + 15 >= off0) jl = max(jl, end0);
    if (qbase + 15 >= off1) jl = max(jl, end1);

    f32x4 ot[4] = {};
    float psA = 0.f, psB = 0.f;

    const u16* Kp = kk + (size_t)bh * 2048 * 64;
    const u16* Vp = vT + (size_t)bh * 64 * 2048;
    u16* Pw = &Plds[wave][0][0];

    for (int jb = 0; jb < jl; jb += 64) {
        f32x4 st[4];
#pragma unroll
        for (int tt = 0; tt < 4; tt++) {
            const u16* Kr = Kp + (size_t)(jb + 16 * tt + r) * 64 + 8 * g;
            short8 kf0 = *(const short8*)Kr;
            short8 kf1 = *(const short8*)(Kr + 32);
            f32x4 z = {};
            z = __builtin_amdgcn_mfma_f32_16x16x32_bf16(kf0, qf0, z, 0, 0, 0);
            z = __builtin_amdgcn_mfma_f32_16x16x32_bf16(kf1, qf1, z, 0, 0, 0);
            st[tt] = z;
        }
#pragma unroll
        for (int tt = 0; tt < 4; tt++) {
            int kvb = jb + 16 * tt + 4 * g;
            float p0, p1, p2, p3;
#pragma unroll
            for (int j = 0; j < 4; j++) {
                float x = st[tt][j];
                float x2 = x * x;
                float inner = __builtin_fmaf(x2, 2.1333333e-8f, -1.3333333e-4f);
                float poly = __builtin_fmaf(x2, inner, 1.0f);
                float pv = __expf(x * poly);
                pv = (kvb + j < rowlim) ? pv : 0.f;
                if (j == 0) p0 = pv; else if (j == 1) p1 = pv;
                else if (j == 2) p2 = pv; else p3 = pv;
            }
            psA += p0 + p1;
            psB += p2 + p3;
            u32 pk0, pk1;
            asm("v_cvt_pk_bf16_f32 %0, %1, %2" : "=v"(pk0) : "v"(p0), "v"(p1));
            asm("v_cvt_pk_bf16_f32 %0, %1, %2" : "=v"(pk1) : "v"(p2), "v"(p3));
            *(u32*)&Pw[r * 72 + 16 * tt + 4 * g] = pk0;
            *(u32*)&Pw[r * 72 + 16 * tt + 4 * g + 2] = pk1;
        }
        short8 pf0 = *(const short8*)&Pw[r * 72 + 8 * g];
        short8 pf1 = *(const short8*)&Pw[r * 72 + 32 + 8 * g];
#pragma unroll
        for (int dt = 0; dt < 4; dt++) {
            const u16* Vr = Vp + (size_t)(dt * 16 + r) * 2048 + jb + 8 * g;
            short8 vf0 = *(const short8*)Vr;
            short8 vf1 = *(const short8*)(Vr + 32);
            ot[dt] = __builtin_amdgcn_mfma_f32_16x16x32_bf16(vf0, pf0, ot[dt], 0, 0, 0);
            ot[dt] = __builtin_amdgcn_mfma_f32_16x16x32_bf16(vf1, pf1, ot[dt], 0, 0, 0);
        }
    }
    float lrow = psA + psB;
    lrow += __shfl_xor(lrow, 16);
    lrow += __shfl_xor(lrow, 32);
    float inv = 1.f / lrow;
    u16* Op = attn_out + ((size_t)(b * 2048 + qbase + r)) * 1024 + h * 64;
#pragma unroll
    for (int dt = 0; dt < 4; dt++) {
        u16x4 o = { f2bf(ot[dt][0] * inv), f2bf(ot[dt][1] * inv),
                    f2bf(ot[dt][2] * inv), f2bf(ot[dt][3] * inv) };
        *(u16x4*)(Op + dt * 16 + 4 * g) = o;
    }
}

extern "C" void kernel_launch(void* const* d_in, const int* in_sizes, int n_in,
                              void* d_out, int out_size, void* d_ws, size_t ws_size,
                              hipStream_t stream) {
    const float* x = (const float*)d_in[0];
    const float* gamma = (const float*)d_in[1];
    const float* w_qkv = (const float*)d_in[2];
    const float* w_out = (const float*)d_in[3];
    const int* mods = (const int*)d_in[4];
    float* out = (float*)d_out;

    u16* ws = (u16*)d_ws;
    u16* xn    = ws;                 // 4096*2048
    u16* wqkvT = ws + 8388608;       // 3072*2048
    u16* woutT = ws + 14680064;      // 2048*1024
    u16* qb    = ws + 16777216;      // 2*16*2048*64
    u16* kb    = ws + 20971520;
    u16* vT    = ws + 25165824;
    u16* ao    = ws + 29360128;      // 4096*1024

    transpose_cast<<<dim3(96, 64), dim3(32, 8), 0, stream>>>(w_qkv, wqkvT, 2048, 3072);
    transpose_cast<<<dim3(64, 32), dim3(32, 8), 0, stream>>>(w_out, woutT, 1024, 2048);
    rmsnorm_cast<<<dim3(4096), dim3(256), 0, stream>>>(x, gamma, xn);
    gemm_bt<0><<<dim3(24, 32), dim3(256), 0, stream>>>(xn, wqkvT, 4096, 3072, 2048,
                                                       nullptr, qb, kb, vT);
    flash_attn<<<dim3(32, 16, 2), dim3(256), 0, stream>>>(qb, kb, vT, mods, ao);
    gemm_bt<1><<<dim3(16, 32), dim3(256), 0, stream>>>(ao, woutT, 4096, 2048, 1024,
                                                       out, nullptr, nullptr, nullptr);
}

// Round 3
// 222.310 us; speedup vs baseline: 1.8289x; 1.8138x over previous
//
#include <hip/hip_runtime.h>
#include <hip/hip_bf16.h>

typedef unsigned short u16;
typedef unsigned int u32;
typedef __attribute__((ext_vector_type(8))) short short8;
typedef __attribute__((ext_vector_type(4))) float f32x4;
typedef __attribute__((ext_vector_type(4))) u16 u16x4;

#define DEV __device__ __forceinline__

DEV u16 f2bf(float f) {
    union { float f; u32 u; } v; v.f = f;
    u32 r = v.u;
    u32 lsb = (r >> 16) & 1u;
    r += 0x7fffu + lsb;
    return (u16)(r >> 16);
}

DEV void gload_lds16(const u16* g, u16* l) {
    __builtin_amdgcn_global_load_lds(
        (const __attribute__((address_space(1))) u32*)(const void*)g,
        (__attribute__((address_space(3))) u32*)(void*)l,
        16, 0, 0);
}

// ---------------- transpose + cast: in[R][C] fp32 -> out[C][R] bf16 ----------------
__global__ void transpose_cast(const float* __restrict__ in, u16* __restrict__ out,
                               int R, int C) {
    __shared__ float tile[32][33];
    int c0 = blockIdx.x * 32, r0 = blockIdx.y * 32;
    int tx = threadIdx.x, ty = threadIdx.y; // 32 x 8
#pragma unroll
    for (int i = 0; i < 4; i++)
        tile[ty * 4 + i][tx] = in[(size_t)(r0 + ty * 4 + i) * C + c0 + tx];
    __syncthreads();
#pragma unroll
    for (int i = 0; i < 4; i++)
        out[(size_t)(c0 + ty * 4 + i) * R + r0 + tx] = f2bf(tile[tx][ty * 4 + i]);
}

// ---------------- RMSNorm + cast to bf16: x[4096][2048] -> xn ----------------
__global__ void rmsnorm_cast(const float* __restrict__ x, const float* __restrict__ gamma,
                             u16* __restrict__ xn) {
    int row = blockIdx.x;
    int t = threadIdx.x; // 256
    const float4* xr = (const float4*)(x + (size_t)row * 2048);
    float4 a = xr[t];
    float4 b = xr[256 + t];
    float ss = a.x * a.x + a.y * a.y + a.z * a.z + a.w * a.w +
               b.x * b.x + b.y * b.y + b.z * b.z + b.w * b.w;
#pragma unroll
    for (int off = 32; off; off >>= 1) ss += __shfl_xor(ss, off);
    __shared__ float red[4];
    if ((t & 63) == 0) red[t >> 6] = ss;
    __syncthreads();
    float tot = red[0] + red[1] + red[2] + red[3];
    float n = sqrtf(tot);
    float inv = 45.254833995939045f / fmaxf(n, 1e-12f); // sqrt(2048)/max(n,eps)
    const float4* gr = (const float4*)gamma;
    float4 g0 = gr[t], g1 = gr[256 + t];
    u16x4 o0 = { f2bf(a.x * inv * (g0.x + 1.f)), f2bf(a.y * inv * (g0.y + 1.f)),
                 f2bf(a.z * inv * (g0.z + 1.f)), f2bf(a.w * inv * (g0.w + 1.f)) };
    u16x4 o1 = { f2bf(b.x * inv * (g1.x + 1.f)), f2bf(b.y * inv * (g1.y + 1.f)),
                 f2bf(b.z * inv * (g1.z + 1.f)), f2bf(b.w * inv * (g1.w + 1.f)) };
    u16x4* xo = (u16x4*)(xn + (size_t)row * 2048);
    xo[t] = o0;
    xo[256 + t] = o1;
}

// ---------------- GEMM: C[M,N] = A[M,K] @ BT[N,K]^T (bf16 in, fp32 acc) ----------------
template <int EPI>
__global__ __launch_bounds__(256, 2) void gemm_bt(
    const u16* __restrict__ A, const u16* __restrict__ BT,
    int M, int N, int K,
    float* __restrict__ Cout,
    u16* __restrict__ qb, u16* __restrict__ kb, u16* __restrict__ vT) {
    __shared__ __align__(16) u16 As[4096];
    __shared__ __align__(16) u16 Bs[4096];
    int t = threadIdx.x;
    int lane = t & 63, wave = t >> 6;
    int g = lane >> 4, r = lane & 15;
    int brow = blockIdx.y * 128, bcol = blockIdx.x * 128;
    int wr = (wave >> 1) * 64, wc = (wave & 1) * 64;

    f32x4 acc[4][4] = {};

    int g0 = t >> 7, row0 = t & 127;
    int g1 = (256 + t) >> 7, row1 = t & 127;
    const u16* Arow0 = A + (size_t)(brow + row0) * K + g0 * 8;
    const u16* Arow1 = A + (size_t)(brow + row1) * K + g1 * 8;
    const u16* Brow0 = BT + (size_t)(bcol + row0) * K + g0 * 8;
    const u16* Brow1 = BT + (size_t)(bcol + row1) * K + g1 * 8;
    u16* lA0 = As + wave * 512;
    u16* lA1 = As + 2048 + wave * 512;
    u16* lB0 = Bs + wave * 512;
    u16* lB1 = Bs + 2048 + wave * 512;

    for (int k0 = 0; k0 < K; k0 += 32) {
        __syncthreads();
        gload_lds16(Arow0 + k0, lA0);
        gload_lds16(Arow1 + k0, lA1);
        gload_lds16(Brow0 + k0, lB0);
        gload_lds16(Brow1 + k0, lB1);
        __syncthreads();
        short8 af[4], bf[4];
#pragma unroll
        for (int m = 0; m < 4; m++)
            af[m] = *(const short8*)&As[(size_t)(g * 128 + wr + m * 16 + r) * 8];
#pragma unroll
        for (int n = 0; n < 4; n++)
            bf[n] = *(const short8*)&Bs[(size_t)(g * 128 + wc + n * 16 + r) * 8];
#pragma unroll
        for (int m = 0; m < 4; m++)
#pragma unroll
            for (int n = 0; n < 4; n++)
                acc[m][n] = __builtin_amdgcn_mfma_f32_16x16x32_bf16(af[m], bf[n], acc[m][n], 0, 0, 0);
    }

    if (EPI == 0) {
#pragma unroll
        for (int m = 0; m < 4; m++)
#pragma unroll
            for (int n = 0; n < 4; n++) {
                int cb = bcol + wc + n * 16 + r;
                int which = cb >> 10;
                int hd = cb & 1023;
                int h = hd >> 6, d = hd & 63;
#pragma unroll
                for (int j = 0; j < 4; j++) {
                    int rr = brow + wr + m * 16 + 4 * g + j;
                    int b = rr >> 11, nn = rr & 2047;
                    float v = acc[m][n][j];
                    size_t bh = (size_t)(b * 16 + h);
                    if (which == 0)      qb[(bh * 2048 + nn) * 64 + d] = f2bf(v * 0.125f);
                    else if (which == 1) kb[(bh * 2048 + nn) * 64 + d] = f2bf(v);
                    else                 vT[(bh * 64 + d) * 2048 + nn] = f2bf(v);
                }
            }
    } else {
#pragma unroll
        for (int m = 0; m < 4; m++)
#pragma unroll
            for (int n = 0; n < 4; n++) {
                int cb = bcol + wc + n * 16 + r;
#pragma unroll
                for (int j = 0; j < 4; j++) {
                    int rr = brow + wr + m * 16 + 4 * g + j;
                    Cout[(size_t)rr * N + cb] = acc[m][n][j];
                }
            }
    }
}

// ---------------- flash attention v3: block-shared LDS K/V, double-buffered ----------------
// Block = 64 q rows of one (b,h); 4 waves, 16 rows each.
// K tile [64 kv][64 d], V tile [64 d][64 kv] staged in LDS via global_load_lds,
// 16B chunks XOR-swizzled: chunk_lin = chunk ^ (row & 7) (both sides).
// Softcap bounds s => fixed-max softmax (no running max). Mask = kv < rowlim.
__global__ __launch_bounds__(256, 3) void flash_attn(
    const u16* __restrict__ q, const u16* __restrict__ kk, const u16* __restrict__ vT,
    const int* __restrict__ mods, u16* __restrict__ attn_out) {
    __shared__ __align__(16) u16 Ks[2][4096];
    __shared__ __align__(16) u16 Vs[2][4096];
    __shared__ __align__(16) u16 Plds[4][16][72];
    int t = threadIdx.x, lane = t & 63, wave = t >> 6;
    int g = lane >> 4, r = lane & 15;
    int h = blockIdx.x, b = blockIdx.y;
    int qs = (31 - blockIdx.z) * 64;          // longest q-blocks dispatched first
    int bh = b * 16 + h;
    int qbase = qs + wave * 16;

    int off0 = mods[b * 6 + 1], end0 = off0 + mods[b * 6 + 2];
    int off1 = mods[b * 6 + 4], end1 = off1 + mods[b * 6 + 5];

    const u16* Qp = q + ((size_t)bh * 2048 + qbase) * 64;
    short8 qf0 = *(const short8*)(Qp + (size_t)r * 64 + 8 * g);
    short8 qf1 = *(const short8*)(Qp + (size_t)r * 64 + 32 + 8 * g);

    int iq = qbase + r;
    int lim0 = (iq >= off0) ? end0 : 0;
    int lim1 = (iq >= off1) ? end1 : 0;
    int rowlim = max(iq + 1, max(lim0, lim1));

    // block-uniform KV extent
    int jlb = qs + 64;
    if (qs + 63 >= off0) jlb = max(jlb, end0);
    if (qs + 63 >= off1) jlb = max(jlb, end1);

    const u16* Kp = kk + (size_t)bh * 2048 * 64;
    const u16* Vp = vT + (size_t)bh * 64 * 2048;
    u16* Pw = &Plds[wave][0][0];

    f32x4 ot[4] = {};
    float psA = 0.f, psB = 0.f;
    int sw = r & 7;

    // stage one 64x64 bf16 tile (8KB = 512 chunks of 16B); 2 calls/thread.
    // chunk c at (row = c>>3, lin = c&7) holds global chunk (c&7)^(row&7).
    auto stage64 = [&](const u16* gbase, int gstride, u16* lds) {
#pragma unroll
        for (int i = 0; i < 2; i++) {
            int c = i * 256 + t;
            int row = c >> 3;
            int gsl = (c & 7) ^ (row & 7);
            gload_lds16(gbase + (size_t)row * gstride + 8 * gsl,
                        lds + (size_t)(c & ~63) * 8);
        }
    };

    stage64(Kp, 64, Ks[0]);
    stage64(Vp, 2048, Vs[0]);
    int buf = 0;

    for (int jb = 0; jb < jlb; jb += 64) {
        if (jb + 64 < jlb) {
            stage64(Kp + (size_t)(jb + 64) * 64, 64, Ks[buf ^ 1]);
            stage64(Vp + (jb + 64), 2048, Vs[buf ^ 1]);
            asm volatile("s_waitcnt vmcnt(4)" ::: "memory"); // current buf done, prefetch in flight
        } else {
            asm volatile("s_waitcnt vmcnt(0)" ::: "memory");
        }
        __builtin_amdgcn_s_barrier();
        const u16* Kt = Ks[buf];
        const u16* Vt = Vs[buf];

        // QK^T (swapped: lane holds S[kv = 4g+j within tt][q = r])
        f32x4 st[4];
#pragma unroll
        for (int tt = 0; tt < 4; tt++) {
            int row = 16 * tt + r;
            short8 kf0 = *(const short8*)&Kt[(size_t)(row * 8 + (g ^ sw)) * 8];
            short8 kf1 = *(const short8*)&Kt[(size_t)(row * 8 + ((4 + g) ^ sw)) * 8];
            f32x4 z = {};
            z = __builtin_amdgcn_mfma_f32_16x16x32_bf16(kf0, qf0, z, 0, 0, 0);
            z = __builtin_amdgcn_mfma_f32_16x16x32_bf16(kf1, qf1, z, 0, 0, 0);
            st[tt] = z;
        }
        // softcap (odd poly) + mask + exp (no running max: |s|<=50)
#pragma unroll
        for (int tt = 0; tt < 4; tt++) {
            int kvb = jb + 16 * tt + 4 * g;
            float p0, p1, p2, p3;
#pragma unroll
            for (int j = 0; j < 4; j++) {
                float x = st[tt][j];
                float x2 = x * x;
                float inner = __builtin_fmaf(x2, 2.1333333e-8f, -1.3333333e-4f);
                float poly = __builtin_fmaf(x2, inner, 1.0f);
                float pv = __expf(x * poly);
                pv = (kvb + j < rowlim) ? pv : 0.f;
                if (j == 0) p0 = pv; else if (j == 1) p1 = pv;
                else if (j == 2) p2 = pv; else p3 = pv;
            }
            psA += p0 + p1;
            psB += p2 + p3;
            u32 pk0, pk1;
            asm("v_cvt_pk_bf16_f32 %0, %1, %2" : "=v"(pk0) : "v"(p0), "v"(p1));
            asm("v_cvt_pk_bf16_f32 %0, %1, %2" : "=v"(pk1) : "v"(p2), "v"(p3));
            *(u32*)&Pw[r * 72 + 16 * tt + 4 * g] = pk0;
            *(u32*)&Pw[r * 72 + 16 * tt + 4 * g + 2] = pk1;
        }
        short8 pf0 = *(const short8*)&Pw[r * 72 + 8 * g];
        short8 pf1 = *(const short8*)&Pw[r * 72 + 32 + 8 * g];
        // PV: O[d][q] += V^T[d][kv] P[kv][q]
#pragma unroll
        for (int dt = 0; dt < 4; dt++) {
            int row = 16 * dt + r;
            short8 vf0 = *(const short8*)&Vt[(size_t)(row * 8 + (g ^ sw)) * 8];
            short8 vf1 = *(const short8*)&Vt[(size_t)(row * 8 + ((4 + g) ^ sw)) * 8];
            ot[dt] = __builtin_amdgcn_mfma_f32_16x16x32_bf16(vf0, pf0, ot[dt], 0, 0, 0);
            ot[dt] = __builtin_amdgcn_mfma_f32_16x16x32_bf16(vf1, pf1, ot[dt], 0, 0, 0);
        }
        asm volatile("s_waitcnt lgkmcnt(0)" ::: "memory"); // drain LDS reads, keep prefetch in flight
        __builtin_amdgcn_s_barrier();
        buf ^= 1;
    }

    float lrow = psA + psB;
    lrow += __shfl_xor(lrow, 16);
    lrow += __shfl_xor(lrow, 32);
    float inv = 1.f / lrow;
    u16* Op = attn_out + ((size_t)(b * 2048 + qbase + r)) * 1024 + h * 64;
#pragma unroll
    for (int dt = 0; dt < 4; dt++) {
        u16x4 o = { f2bf(ot[dt][0] * inv), f2bf(ot[dt][1] * inv),
                    f2bf(ot[dt][2] * inv), f2bf(ot[dt][3] * inv) };
        *(u16x4*)(Op + dt * 16 + 4 * g) = o;
    }
}

extern "C" void kernel_launch(void* const* d_in, const int* in_sizes, int n_in,
                              void* d_out, int out_size, void* d_ws, size_t ws_size,
                              hipStream_t stream) {
    const float* x = (const float*)d_in[0];
    const float* gamma = (const float*)d_in[1];
    const float* w_qkv = (const float*)d_in[2];
    const float* w_out = (const float*)d_in[3];
    const int* mods = (const int*)d_in[4];
    float* out = (float*)d_out;

    u16* ws = (u16*)d_ws;
    u16* xn    = ws;                 // 4096*2048
    u16* wqkvT = ws + 8388608;       // 3072*2048
    u16* woutT = ws + 14680064;      // 2048*1024
    u16* qb    = ws + 16777216;      // 2*16*2048*64
    u16* kb    = ws + 20971520;
    u16* vT    = ws + 25165824;
    u16* ao    = ws + 29360128;      // 4096*1024

    transpose_cast<<<dim3(96, 64), dim3(32, 8), 0, stream>>>(w_qkv, wqkvT, 2048, 3072);
    transpose_cast<<<dim3(64, 32), dim3(32, 8), 0, stream>>>(w_out, woutT, 1024, 2048);
    rmsnorm_cast<<<dim3(4096), dim3(256), 0, stream>>>(x, gamma, xn);
    gemm_bt<0><<<dim3(24, 32), dim3(256), 0, stream>>>(xn, wqkvT, 4096, 3072, 2048,
                                                       nullptr, qb, kb, vT);
    flash_attn<<<dim3(16, 2, 32), dim3(256), 0, stream>>>(qb, kb, vT, mods, ao);
    gemm_bt<1><<<dim3(16, 32), dim3(256), 0, stream>>>(ao, woutT, 4096, 2048, 1024,
                                                       out, nullptr, nullptr, nullptr);
}

// Round 4
// 221.970 us; speedup vs baseline: 1.8317x; 1.0015x over previous
//
#include <hip/hip_runtime.h>
#include <hip/hip_bf16.h>

typedef unsigned short u16;
typedef unsigned int u32;
typedef __attribute__((ext_vector_type(8))) short short8;
typedef __attribute__((ext_vector_type(4))) float f32x4;
typedef __attribute__((ext_vector_type(4))) u16 u16x4;

#define DEV __device__ __forceinline__

DEV u16 f2bf(float f) {
    union { float f; u32 u; } v; v.f = f;
    u32 r = v.u;
    u32 lsb = (r >> 16) & 1u;
    r += 0x7fffu + lsb;
    return (u16)(r >> 16);
}

DEV void gload_lds16(const u16* g, u16* l) {
    __builtin_amdgcn_global_load_lds(
        (const __attribute__((address_space(1))) u32*)(const void*)g,
        (__attribute__((address_space(3))) u32*)(void*)l,
        16, 0, 0);
}

// ---------------- transpose + cast: in[R][C] fp32 -> out[C][R] bf16 ----------------
__global__ void transpose_cast(const float* __restrict__ in, u16* __restrict__ out,
                               int R, int C) {
    __shared__ float tile[32][33];
    int c0 = blockIdx.x * 32, r0 = blockIdx.y * 32;
    int tx = threadIdx.x, ty = threadIdx.y; // 32 x 8
#pragma unroll
    for (int i = 0; i < 4; i++)
        tile[ty * 4 + i][tx] = in[(size_t)(r0 + ty * 4 + i) * C + c0 + tx];
    __syncthreads();
#pragma unroll
    for (int i = 0; i < 4; i++)
        out[(size_t)(c0 + ty * 4 + i) * R + r0 + tx] = f2bf(tile[tx][ty * 4 + i]);
}

// ---------------- RMSNorm + cast to bf16: x[4096][2048] -> xn ----------------
__global__ void rmsnorm_cast(const float* __restrict__ x, const float* __restrict__ gamma,
                             u16* __restrict__ xn) {
    int row = blockIdx.x;
    int t = threadIdx.x; // 256
    const float4* xr = (const float4*)(x + (size_t)row * 2048);
    float4 a = xr[t];
    float4 b = xr[256 + t];
    float ss = a.x * a.x + a.y * a.y + a.z * a.z + a.w * a.w +
               b.x * b.x + b.y * b.y + b.z * b.z + b.w * b.w;
#pragma unroll
    for (int off = 32; off; off >>= 1) ss += __shfl_xor(ss, off);
    __shared__ float red[4];
    if ((t & 63) == 0) red[t >> 6] = ss;
    __syncthreads();
    float tot = red[0] + red[1] + red[2] + red[3];
    float n = sqrtf(tot);
    float inv = 45.254833995939045f / fmaxf(n, 1e-12f); // sqrt(2048)/max(n,eps)
    const float4* gr = (const float4*)gamma;
    float4 g0 = gr[t], g1 = gr[256 + t];
    u16x4 o0 = { f2bf(a.x * inv * (g0.x + 1.f)), f2bf(a.y * inv * (g0.y + 1.f)),
                 f2bf(a.z * inv * (g0.z + 1.f)), f2bf(a.w * inv * (g0.w + 1.f)) };
    u16x4 o1 = { f2bf(b.x * inv * (g1.x + 1.f)), f2bf(b.y * inv * (g1.y + 1.f)),
                 f2bf(b.z * inv * (g1.z + 1.f)), f2bf(b.w * inv * (g1.w + 1.f)) };
    u16x4* xo = (u16x4*)(xn + (size_t)row * 2048);
    xo[t] = o0;
    xo[256 + t] = o1;
}

// ---------------- pipelined GEMM: C[M,N] = A[M,K] @ BT[N,K]^T ----------------
// 128x128 tile, BK=32, 4 waves (2Mx2N), 3 LDS buffers, prefetch 2 tiles ahead,
// counted vmcnt at tile boundary (never 0 mid-loop), 1 barrier/tile, setprio,
// bijective XCD swizzle on a 1-D grid (nwg % 8 == 0).
template <int EPI>
__global__ __launch_bounds__(256, 3) void gemm_pipe(
    const u16* __restrict__ A, const u16* __restrict__ BT,
    int M, int N, int K, int nbx,
    float* __restrict__ Cout,
    u16* __restrict__ qb, u16* __restrict__ kb, u16* __restrict__ vT) {
    __shared__ __align__(16) u16 As[3][4096];
    __shared__ __align__(16) u16 Bs[3][4096];
    int t = threadIdx.x, lane = t & 63, wid = t >> 6;
    int g = lane >> 4, r = lane & 15;
    int wm = wid >> 1, wn = wid & 1;

    int nwg = gridDim.x;
    int id = blockIdx.x;
    int wg = (id & 7) * (nwg >> 3) + (id >> 3); // XCD-aware swizzle (nwg%8==0)
    int bx = wg % nbx, by = wg / nbx;
    int brow = by * 128, bcol = bx * 128;

    // staging: chunk c (16B) at LDS u16-offset c*8 holds (row=c&127, g=c>>7);
    // loads i=0: c=t, i=1: c=256+t (same row, g+2 => src +16 u16)
    int rS = t & 127, gS = t >> 7;
    const u16* Ag0 = A + (size_t)(brow + rS) * K + gS * 8;
    const u16* Bg0 = BT + (size_t)(bcol + rS) * K + gS * 8;
    int dst0 = (t & ~63) * 8;
    int dst1 = 2048 + dst0;

    f32x4 acc[4][4] = {};
    int NT = K >> 5;

#define GISSUE(kt_) { int b_ = (kt_) % 3; int ko_ = (kt_) << 5;                \
        gload_lds16(Ag0 + ko_,      &As[b_][dst0]);                            \
        gload_lds16(Ag0 + ko_ + 16, &As[b_][dst1]);                            \
        gload_lds16(Bg0 + ko_,      &Bs[b_][dst0]);                            \
        gload_lds16(Bg0 + ko_ + 16, &Bs[b_][dst1]); }

    GISSUE(0);
    GISSUE(1);
    asm volatile("s_waitcnt vmcnt(4)" ::: "memory"); // tile0 landed, tile1 in flight
    asm volatile("s_barrier" ::: "memory");

    for (int kt = 0; kt < NT; ++kt) {
        int cur = kt % 3;
        bool pre = (kt + 2 < NT);
        if (pre) GISSUE(kt + 2); // into buffer retired at tile kt-1
        const u16* Ab = As[cur];
        const u16* Bb = Bs[cur];
        short8 af[4], bf[4];
#pragma unroll
        for (int m = 0; m < 4; m++)
            af[m] = *(const short8*)&Ab[(size_t)(g * 128 + wm * 64 + m * 16 + r) * 8];
#pragma unroll
        for (int n = 0; n < 4; n++)
            bf[n] = *(const short8*)&Bb[(size_t)(g * 128 + wn * 64 + n * 16 + r) * 8];
        __builtin_amdgcn_s_setprio(1);
#pragma unroll
        for (int m = 0; m < 4; m++)
#pragma unroll
            for (int n = 0; n < 4; n++)
                acc[m][n] = __builtin_amdgcn_mfma_f32_16x16x32_bf16(af[m], bf[n], acc[m][n], 0, 0, 0);
        __builtin_amdgcn_s_setprio(0);
        if (pre) { asm volatile("s_waitcnt vmcnt(4)" ::: "memory"); } // next tile landed
        else     { asm volatile("s_waitcnt vmcnt(0)" ::: "memory"); }
        asm volatile("s_barrier" ::: "memory");
    }
#undef GISSUE

    if (EPI == 0) {
#pragma unroll
        for (int m = 0; m < 4; m++)
#pragma unroll
            for (int n = 0; n < 4; n++) {
                int cb = bcol + wn * 64 + n * 16 + r;
                int which = cb >> 10;
                int hd = cb & 1023;
                int h = hd >> 6, d = hd & 63;
#pragma unroll
                for (int j = 0; j < 4; j++) {
                    int rr = brow + wm * 64 + m * 16 + 4 * g + j;
                    int b = rr >> 11, nn = rr & 2047;
                    float v = acc[m][n][j];
                    size_t bh = (size_t)(b * 16 + h);
                    if (which == 0)      qb[(bh * 2048 + nn) * 64 + d] = f2bf(v * 0.125f);
                    else if (which == 1) kb[(bh * 2048 + nn) * 64 + d] = f2bf(v);
                    else                 vT[(bh * 64 + d) * 2048 + nn] = f2bf(v);
                }
            }
    } else {
#pragma unroll
        for (int m = 0; m < 4; m++)
#pragma unroll
            for (int n = 0; n < 4; n++) {
                int cb = bcol + wn * 64 + n * 16 + r;
#pragma unroll
                for (int j = 0; j < 4; j++) {
                    int rr = brow + wm * 64 + m * 16 + 4 * g + j;
                    Cout[(size_t)rr * N + cb] = acc[m][n][j];
                }
            }
    }
}

// ---------------- flash attention v3: block-shared LDS K/V, double-buffered ----------------
__global__ __launch_bounds__(256, 3) void flash_attn(
    const u16* __restrict__ q, const u16* __restrict__ kk, const u16* __restrict__ vT,
    const int* __restrict__ mods, u16* __restrict__ attn_out) {
    __shared__ __align__(16) u16 Ks[2][4096];
    __shared__ __align__(16) u16 Vs[2][4096];
    __shared__ __align__(16) u16 Plds[4][16][72];
    int t = threadIdx.x, lane = t & 63, wave = t >> 6;
    int g = lane >> 4, r = lane & 15;
    int h = blockIdx.x, b = blockIdx.y;
    int qs = (31 - blockIdx.z) * 64;          // longest q-blocks dispatched first
    int bh = b * 16 + h;
    int qbase = qs + wave * 16;

    int off0 = mods[b * 6 + 1], end0 = off0 + mods[b * 6 + 2];
    int off1 = mods[b * 6 + 4], end1 = off1 + mods[b * 6 + 5];

    const u16* Qp = q + ((size_t)bh * 2048 + qbase) * 64;
    short8 qf0 = *(const short8*)(Qp + (size_t)r * 64 + 8 * g);
    short8 qf1 = *(const short8*)(Qp + (size_t)r * 64 + 32 + 8 * g);

    int iq = qbase + r;
    int lim0 = (iq >= off0) ? end0 : 0;
    int lim1 = (iq >= off1) ? end1 : 0;
    int rowlim = max(iq + 1, max(lim0, lim1));

    int jlb = qs + 64;
    if (qs + 63 >= off0) jlb = max(jlb, end0);
    if (qs + 63 >= off1) jlb = max(jlb, end1);

    const u16* Kp = kk + (size_t)bh * 2048 * 64;
    const u16* Vp = vT + (size_t)bh * 64 * 2048;
    u16* Pw = &Plds[wave][0][0];

    f32x4 ot[4] = {};
    float psA = 0.f, psB = 0.f;
    int sw = r & 7;

    auto stage64 = [&](const u16* gbase, int gstride, u16* lds) {
#pragma unroll
        for (int i = 0; i < 2; i++) {
            int c = i * 256 + t;
            int row = c >> 3;
            int gsl = (c & 7) ^ (row & 7);
            gload_lds16(gbase + (size_t)row * gstride + 8 * gsl,
                        lds + (size_t)(c & ~63) * 8);
        }
    };

    stage64(Kp, 64, Ks[0]);
    stage64(Vp, 2048, Vs[0]);
    int buf = 0;

    for (int jb = 0; jb < jlb; jb += 64) {
        if (jb + 64 < jlb) {
            stage64(Kp + (size_t)(jb + 64) * 64, 64, Ks[buf ^ 1]);
            stage64(Vp + (jb + 64), 2048, Vs[buf ^ 1]);
            asm volatile("s_waitcnt vmcnt(4)" ::: "memory");
        } else {
            asm volatile("s_waitcnt vmcnt(0)" ::: "memory");
        }
        __builtin_amdgcn_s_barrier();
        const u16* Kt = Ks[buf];
        const u16* Vt = Vs[buf];

        f32x4 st[4];
#pragma unroll
        for (int tt = 0; tt < 4; tt++) {
            int row = 16 * tt + r;
            short8 kf0 = *(const short8*)&Kt[(size_t)(row * 8 + (g ^ sw)) * 8];
            short8 kf1 = *(const short8*)&Kt[(size_t)(row * 8 + ((4 + g) ^ sw)) * 8];
            f32x4 z = {};
            z = __builtin_amdgcn_mfma_f32_16x16x32_bf16(kf0, qf0, z, 0, 0, 0);
            z = __builtin_amdgcn_mfma_f32_16x16x32_bf16(kf1, qf1, z, 0, 0, 0);
            st[tt] = z;
        }
#pragma unroll
        for (int tt = 0; tt < 4; tt++) {
            int kvb = jb + 16 * tt + 4 * g;
            float p0, p1, p2, p3;
#pragma unroll
            for (int j = 0; j < 4; j++) {
                float x = st[tt][j];
                float x2 = x * x;
                float inner = __builtin_fmaf(x2, 2.1333333e-8f, -1.3333333e-4f);
                float poly = __builtin_fmaf(x2, inner, 1.0f);
                float pv = __expf(x * poly);
                pv = (kvb + j < rowlim) ? pv : 0.f;
                if (j == 0) p0 = pv; else if (j == 1) p1 = pv;
                else if (j == 2) p2 = pv; else p3 = pv;
            }
            psA += p0 + p1;
            psB += p2 + p3;
            u32 pk0, pk1;
            asm("v_cvt_pk_bf16_f32 %0, %1, %2" : "=v"(pk0) : "v"(p0), "v"(p1));
            asm("v_cvt_pk_bf16_f32 %0, %1, %2" : "=v"(pk1) : "v"(p2), "v"(p3));
            *(u32*)&Pw[r * 72 + 16 * tt + 4 * g] = pk0;
            *(u32*)&Pw[r * 72 + 16 * tt + 4 * g + 2] = pk1;
        }
        short8 pf0 = *(const short8*)&Pw[r * 72 + 8 * g];
        short8 pf1 = *(const short8*)&Pw[r * 72 + 32 + 8 * g];
#pragma unroll
        for (int dt = 0; dt < 4; dt++) {
            int row = 16 * dt + r;
            short8 vf0 = *(const short8*)&Vt[(size_t)(row * 8 + (g ^ sw)) * 8];
            short8 vf1 = *(const short8*)&Vt[(size_t)(row * 8 + ((4 + g) ^ sw)) * 8];
            ot[dt] = __builtin_amdgcn_mfma_f32_16x16x32_bf16(vf0, pf0, ot[dt], 0, 0, 0);
            ot[dt] = __builtin_amdgcn_mfma_f32_16x16x32_bf16(vf1, pf1, ot[dt], 0, 0, 0);
        }
        asm volatile("s_waitcnt lgkmcnt(0)" ::: "memory");
        __builtin_amdgcn_s_barrier();
        buf ^= 1;
    }

    float lrow = psA + psB;
    lrow += __shfl_xor(lrow, 16);
    lrow += __shfl_xor(lrow, 32);
    float inv = 1.f / lrow;
    u16* Op = attn_out + ((size_t)(b * 2048 + qbase + r)) * 1024 + h * 64;
#pragma unroll
    for (int dt = 0; dt < 4; dt++) {
        u16x4 o = { f2bf(ot[dt][0] * inv), f2bf(ot[dt][1] * inv),
                    f2bf(ot[dt][2] * inv), f2bf(ot[dt][3] * inv) };
        *(u16x4*)(Op + dt * 16 + 4 * g) = o;
    }
}

extern "C" void kernel_launch(void* const* d_in, const int* in_sizes, int n_in,
                              void* d_out, int out_size, void* d_ws, size_t ws_size,
                              hipStream_t stream) {
    const float* x = (const float*)d_in[0];
    const float* gamma = (const float*)d_in[1];
    const float* w_qkv = (const float*)d_in[2];
    const float* w_out = (const float*)d_in[3];
    const int* mods = (const int*)d_in[4];
    float* out = (float*)d_out;

    u16* ws = (u16*)d_ws;
    u16* xn    = ws;                 // 4096*2048
    u16* wqkvT = ws + 8388608;       // 3072*2048
    u16* woutT = ws + 14680064;      // 2048*1024
    u16* qb    = ws + 16777216;      // 2*16*2048*64
    u16* kb    = ws + 20971520;
    u16* vT    = ws + 25165824;
    u16* ao    = ws + 29360128;      // 4096*1024

    transpose_cast<<<dim3(96, 64), dim3(32, 8), 0, stream>>>(w_qkv, wqkvT, 2048, 3072);
    transpose_cast<<<dim3(64, 32), dim3(32, 8), 0, stream>>>(w_out, woutT, 1024, 2048);
    rmsnorm_cast<<<dim3(4096), dim3(256), 0, stream>>>(x, gamma, xn);
    gemm_pipe<0><<<dim3(768), dim3(256), 0, stream>>>(xn, wqkvT, 4096, 3072, 2048, 24,
                                                      nullptr, qb, kb, vT);
    flash_attn<<<dim3(16, 2, 32), dim3(256), 0, stream>>>(qb, kb, vT, mods, ao);
    gemm_pipe<1><<<dim3(512), dim3(256), 0, stream>>>(ao, woutT, 4096, 2048, 1024, 16,
                                                      out, nullptr, nullptr, nullptr);
}

// Round 5
// 195.927 us; speedup vs baseline: 2.0752x; 1.1329x over previous
//
#include <hip/hip_runtime.h>
#include <hip/hip_bf16.h>

typedef unsigned short u16;
typedef unsigned int u32;
typedef __attribute__((ext_vector_type(8))) short short8;
typedef __attribute__((ext_vector_type(4))) float f32x4;
typedef __attribute__((ext_vector_type(4))) u16 u16x4;

#define DEV __device__ __forceinline__

DEV u16 f2bf(float f) {
    union { float f; u32 u; } v; v.f = f;
    u32 r = v.u;
    u32 lsb = (r >> 16) & 1u;
    r += 0x7fffu + lsb;
    return (u16)(r >> 16);
}

DEV void gload_lds16(const u16* g, u16* l) {
    __builtin_amdgcn_global_load_lds(
        (const __attribute__((address_space(1))) u32*)(const void*)g,
        (__attribute__((address_space(3))) u32*)(void*)l,
        16, 0, 0);
}

// ---------------- transpose + cast: in[R][C] fp32 -> out[C][R] bf16 ----------------
__global__ void transpose_cast(const float* __restrict__ in, u16* __restrict__ out,
                               int R, int C) {
    __shared__ float tile[32][33];
    int c0 = blockIdx.x * 32, r0 = blockIdx.y * 32;
    int tx = threadIdx.x, ty = threadIdx.y; // 32 x 8
#pragma unroll
    for (int i = 0; i < 4; i++)
        tile[ty * 4 + i][tx] = in[(size_t)(r0 + ty * 4 + i) * C + c0 + tx];
    __syncthreads();
#pragma unroll
    for (int i = 0; i < 4; i++)
        out[(size_t)(c0 + ty * 4 + i) * R + r0 + tx] = f2bf(tile[tx][ty * 4 + i]);
}

// ---------------- RMSNorm + cast to bf16: x[4096][2048] -> xn ----------------
__global__ void rmsnorm_cast(const float* __restrict__ x, const float* __restrict__ gamma,
                             u16* __restrict__ xn) {
    int row = blockIdx.x;
    int t = threadIdx.x; // 256
    const float4* xr = (const float4*)(x + (size_t)row * 2048);
    float4 a = xr[t];
    float4 b = xr[256 + t];
    float ss = a.x * a.x + a.y * a.y + a.z * a.z + a.w * a.w +
               b.x * b.x + b.y * b.y + b.z * b.z + b.w * b.w;
#pragma unroll
    for (int off = 32; off; off >>= 1) ss += __shfl_xor(ss, off);
    __shared__ float red[4];
    if ((t & 63) == 0) red[t >> 6] = ss;
    __syncthreads();
    float tot = red[0] + red[1] + red[2] + red[3];
    float n = sqrtf(tot);
    float inv = 45.254833995939045f / fmaxf(n, 1e-12f); // sqrt(2048)/max(n,eps)
    const float4* gr = (const float4*)gamma;
    float4 g0 = gr[t], g1 = gr[256 + t];
    u16x4 o0 = { f2bf(a.x * inv * (g0.x + 1.f)), f2bf(a.y * inv * (g0.y + 1.f)),
                 f2bf(a.z * inv * (g0.z + 1.f)), f2bf(a.w * inv * (g0.w + 1.f)) };
    u16x4 o1 = { f2bf(b.x * inv * (g1.x + 1.f)), f2bf(b.y * inv * (g1.y + 1.f)),
                 f2bf(b.z * inv * (g1.z + 1.f)), f2bf(b.w * inv * (g1.w + 1.f)) };
    u16x4* xo = (u16x4*)(xn + (size_t)row * 2048);
    xo[t] = o0;
    xo[256 + t] = o1;
}

// ---------------- 256x256 8-phase GEMM: C[M,N] = A[M,K] @ BT[N,K]^T ----------------
// 512 threads = 8 waves (2M x 4N); per-wave output 128x64; BK=64 split in 2 K-halves.
// LDS 128 KiB: [buf][kh] slots of 256 rows x 32 k-elems (64B row stride -> b128
// reads at bank floor). Per K-tile: 4 phases {ds_read 4-8 b128, stage 1 half-tile,
// barrier, lgkmcnt(0), setprio, 16 MFMA, setprio, barrier}; boundary vmcnt(4).
// Slot-retirement schedule: phase p's stage targets a slot whose last read
// completed at phase p-1's lgkmcnt(0) + trailing barrier.
template <int EPI>
__global__ __launch_bounds__(512, 1) void gemm8p(
    const u16* __restrict__ A, const u16* __restrict__ BT,
    int M, int N, int K, int nbx,
    float* __restrict__ Cout,
    u16* __restrict__ qb, u16* __restrict__ kb, u16* __restrict__ vT) {
    __shared__ __align__(16) u16 As[2][2][8192];
    __shared__ __align__(16) u16 Bs[2][2][8192];
    int t = threadIdx.x, lane = t & 63, wid = t >> 6;
    int g = lane >> 4, r = lane & 15;
    int wm = wid >> 2, wn = wid & 3;

    int nwg = gridDim.x;
    int id = blockIdx.x;
    int wg = (id & 7) * (nwg >> 3) + (id >> 3); // XCD swizzle (nwg % 8 == 0)
    int bx = wg % nbx, by = wg / nbx;
    int brow = by * 256, bcol = bx * 256;

    // staging: chunk c = i*512 + t -> row = c>>2 (i*128 + t>>2), cchunk = t&3
    const u16* Ag = A + (size_t)(brow + (t >> 2)) * K + (t & 3) * 8;
    const u16* Bg = BT + (size_t)(bcol + (t >> 2)) * K + (t & 3) * 8;
    const size_t rstep = (size_t)128 * K;
    int dst0 = (t & ~63) * 8;
    int dst1 = 4096 + dst0;

    f32x4 acc[8][4] = {};
    int NT = K >> 6;

#define STG_A(bf_, kt_, kh_) { \
        gload_lds16(Ag + (kt_) * 64 + (kh_) * 32,         &As[bf_][kh_][dst0]); \
        gload_lds16(Ag + rstep + (kt_) * 64 + (kh_) * 32, &As[bf_][kh_][dst1]); }
#define STG_B(bf_, kt_, kh_) { \
        gload_lds16(Bg + (kt_) * 64 + (kh_) * 32,         &Bs[bf_][kh_][dst0]); \
        gload_lds16(Bg + rstep + (kt_) * 64 + (kh_) * 32, &Bs[bf_][kh_][dst1]); }

    // prologue: T0 complete + T1 kh0 (12 loads); leave T1kh0 in flight
    STG_A(0, 0, 0); STG_B(0, 0, 0);
    STG_A(0, 0, 1); STG_B(0, 0, 1);
    STG_A(1, 1, 0); STG_B(1, 1, 0);
    asm volatile("s_waitcnt vmcnt(4)" ::: "memory");
    __builtin_amdgcn_s_barrier();

    for (int kt = 0; kt < NT; ++kt) {
        int buf = kt & 1, ob = buf ^ 1;
        const u16* Ak0 = As[buf][0];
        const u16* Ak1 = As[buf][1];
        const u16* Bk0 = Bs[buf][0];
        const u16* Bk1 = Bs[buf][1];
        bool s1 = kt + 1 < NT, s2 = kt + 2 < NT;
        short8 af[4], bfr[4];

        // ---- phase 1: kk0, m0-3 (B kh0 read here, reused in phase 2) ----
#pragma unroll
        for (int n = 0; n < 4; n++)
            bfr[n] = *(const short8*)&Bk0[(wn * 64 + n * 16 + r) * 32 + g * 8];
#pragma unroll
        for (int m = 0; m < 4; m++)
            af[m] = *(const short8*)&Ak0[(wm * 128 + m * 16 + r) * 32 + g * 8];
        if (s1) STG_A(ob, kt + 1, 1);
        __builtin_amdgcn_s_barrier();
        asm volatile("s_waitcnt lgkmcnt(0)" ::: "memory");
        __builtin_amdgcn_s_setprio(1);
#pragma unroll
        for (int m = 0; m < 4; m++)
#pragma unroll
            for (int n = 0; n < 4; n++)
                acc[m][n] = __builtin_amdgcn_mfma_f32_16x16x32_bf16(af[m], bfr[n], acc[m][n], 0, 0, 0);
        __builtin_amdgcn_s_setprio(0);
        __builtin_amdgcn_s_barrier();

        // ---- phase 2: kk0, m4-7 ----
#pragma unroll
        for (int m = 0; m < 4; m++)
            af[m] = *(const short8*)&Ak0[(wm * 128 + 64 + m * 16 + r) * 32 + g * 8];
        if (s1) STG_B(ob, kt + 1, 1);
        __builtin_amdgcn_s_barrier();
        asm volatile("s_waitcnt lgkmcnt(0)" ::: "memory");
        __builtin_amdgcn_s_setprio(1);
#pragma unroll
        for (int m = 0; m < 4; m++)
#pragma unroll
            for (int n = 0; n < 4; n++)
                acc[4 + m][n] = __builtin_amdgcn_mfma_f32_16x16x32_bf16(af[m], bfr[n], acc[4 + m][n], 0, 0, 0);
        __builtin_amdgcn_s_setprio(0);
        __builtin_amdgcn_s_barrier();

        // ---- phase 3: kk1, m0-3 (A kh0 / B kh0 of this buf retired -> stage kt+2 kh0) ----
#pragma unroll
        for (int n = 0; n < 4; n++)
            bfr[n] = *(const short8*)&Bk1[(wn * 64 + n * 16 + r) * 32 + g * 8];
#pragma unroll
        for (int m = 0; m < 4; m++)
            af[m] = *(const short8*)&Ak1[(wm * 128 + m * 16 + r) * 32 + g * 8];
        if (s2) STG_A(buf, kt + 2, 0);
        __builtin_amdgcn_s_barrier();
        asm volatile("s_waitcnt lgkmcnt(0)" ::: "memory");
        __builtin_amdgcn_s_setprio(1);
#pragma unroll
        for (int m = 0; m < 4; m++)
#pragma unroll
            for (int n = 0; n < 4; n++)
                acc[m][n] = __builtin_amdgcn_mfma_f32_16x16x32_bf16(af[m], bfr[n], acc[m][n], 0, 0, 0);
        __builtin_amdgcn_s_setprio(0);
        __builtin_amdgcn_s_barrier();

        // ---- phase 4: kk1, m4-7 ----
#pragma unroll
        for (int m = 0; m < 4; m++)
            af[m] = *(const short8*)&Ak1[(wm * 128 + 64 + m * 16 + r) * 32 + g * 8];
        if (s2) STG_B(buf, kt + 2, 0);
        __builtin_amdgcn_s_barrier();
        asm volatile("s_waitcnt lgkmcnt(0)" ::: "memory");
        __builtin_amdgcn_s_setprio(1);
#pragma unroll
        for (int m = 0; m < 4; m++)
#pragma unroll
            for (int n = 0; n < 4; n++)
                acc[4 + m][n] = __builtin_amdgcn_mfma_f32_16x16x32_bf16(af[m], bfr[n], acc[4 + m][n], 0, 0, 0);
        __builtin_amdgcn_s_setprio(0);
        // boundary: T(kt+1) must be fully landed; keep T(kt+2)kh0 in flight
        if (s2)      { asm volatile("s_waitcnt vmcnt(4)" ::: "memory"); }
        else if (s1) { asm volatile("s_waitcnt vmcnt(0)" ::: "memory"); }
        __builtin_amdgcn_s_barrier();
    }
#undef STG_A
#undef STG_B

    if (EPI == 0) {
#pragma unroll
        for (int m = 0; m < 8; m++)
#pragma unroll
            for (int n = 0; n < 4; n++) {
                int cb = bcol + wn * 64 + n * 16 + r;
                int which = cb >> 10;
                int hd = cb & 1023;
                int hh = hd >> 6, d = hd & 63;
#pragma unroll
                for (int j = 0; j < 4; j++) {
                    int rr = brow + wm * 128 + m * 16 + 4 * g + j;
                    int b = rr >> 11, nn = rr & 2047;
                    float v = acc[m][n][j];
                    size_t bh = (size_t)(b * 16 + hh);
                    if (which == 0)      qb[(bh * 2048 + nn) * 64 + d] = f2bf(v * 0.125f);
                    else if (which == 1) kb[(bh * 2048 + nn) * 64 + d] = f2bf(v);
                    else                 vT[(bh * 64 + d) * 2048 + nn] = f2bf(v);
                }
            }
    } else {
#pragma unroll
        for (int m = 0; m < 8; m++)
#pragma unroll
            for (int n = 0; n < 4; n++) {
                int cb = bcol + wn * 64 + n * 16 + r;
#pragma unroll
                for (int j = 0; j < 4; j++) {
                    int rr = brow + wm * 128 + m * 16 + 4 * g + j;
                    Cout[(size_t)rr * N + cb] = acc[m][n][j];
                }
            }
    }
}

// ---------------- flash attention v3: block-shared LDS K/V, double-buffered ----------------
__global__ __launch_bounds__(256, 3) void flash_attn(
    const u16* __restrict__ q, const u16* __restrict__ kk, const u16* __restrict__ vT,
    const int* __restrict__ mods, u16* __restrict__ attn_out) {
    __shared__ __align__(16) u16 Ks[2][4096];
    __shared__ __align__(16) u16 Vs[2][4096];
    __shared__ __align__(16) u16 Plds[4][16][72];
    int t = threadIdx.x, lane = t & 63, wave = t >> 6;
    int g = lane >> 4, r = lane & 15;
    int h = blockIdx.x, b = blockIdx.y;
    int qs = (31 - blockIdx.z) * 64;          // longest q-blocks dispatched first
    int bh = b * 16 + h;
    int qbase = qs + wave * 16;

    int off0 = mods[b * 6 + 1], end0 = off0 + mods[b * 6 + 2];
    int off1 = mods[b * 6 + 4], end1 = off1 + mods[b * 6 + 5];

    const u16* Qp = q + ((size_t)bh * 2048 + qbase) * 64;
    short8 qf0 = *(const short8*)(Qp + (size_t)r * 64 + 8 * g);
    short8 qf1 = *(const short8*)(Qp + (size_t)r * 64 + 32 + 8 * g);

    int iq = qbase + r;
    int lim0 = (iq >= off0) ? end0 : 0;
    int lim1 = (iq >= off1) ? end1 : 0;
    int rowlim = max(iq + 1, max(lim0, lim1));

    int jlb = qs + 64;
    if (qs + 63 >= off0) jlb = max(jlb, end0);
    if (qs + 63 >= off1) jlb = max(jlb, end1);

    const u16* Kp = kk + (size_t)bh * 2048 * 64;
    const u16* Vp = vT + (size_t)bh * 64 * 2048;
    u16* Pw = &Plds[wave][0][0];

    f32x4 ot[4] = {};
    float psA = 0.f, psB = 0.f;
    int sw = r & 7;

    auto stage64 = [&](const u16* gbase, int gstride, u16* lds) {
#pragma unroll
        for (int i = 0; i < 2; i++) {
            int c = i * 256 + t;
            int row = c >> 3;
            int gsl = (c & 7) ^ (row & 7);
            gload_lds16(gbase + (size_t)row * gstride + 8 * gsl,
                        lds + (size_t)(c & ~63) * 8);
        }
    };

    stage64(Kp, 64, Ks[0]);
    stage64(Vp, 2048, Vs[0]);
    int buf = 0;

    for (int jb = 0; jb < jlb; jb += 64) {
        if (jb + 64 < jlb) {
            stage64(Kp + (size_t)(jb + 64) * 64, 64, Ks[buf ^ 1]);
            stage64(Vp + (jb + 64), 2048, Vs[buf ^ 1]);
            asm volatile("s_waitcnt vmcnt(4)" ::: "memory");
        } else {
            asm volatile("s_waitcnt vmcnt(0)" ::: "memory");
        }
        __builtin_amdgcn_s_barrier();
        const u16* Kt = Ks[buf];
        const u16* Vt = Vs[buf];

        f32x4 st[4];
#pragma unroll
        for (int tt = 0; tt < 4; tt++) {
            int row = 16 * tt + r;
            short8 kf0 = *(const short8*)&Kt[(size_t)(row * 8 + (g ^ sw)) * 8];
            short8 kf1 = *(const short8*)&Kt[(size_t)(row * 8 + ((4 + g) ^ sw)) * 8];
            f32x4 z = {};
            z = __builtin_amdgcn_mfma_f32_16x16x32_bf16(kf0, qf0, z, 0, 0, 0);
            z = __builtin_amdgcn_mfma_f32_16x16x32_bf16(kf1, qf1, z, 0, 0, 0);
            st[tt] = z;
        }
#pragma unroll
        for (int tt = 0; tt < 4; tt++) {
            int kvb = jb + 16 * tt + 4 * g;
            float p0, p1, p2, p3;
#pragma unroll
            for (int j = 0; j < 4; j++) {
                float x = st[tt][j];
                float x2 = x * x;
                float inner = __builtin_fmaf(x2, 2.1333333e-8f, -1.3333333e-4f);
                float poly = __builtin_fmaf(x2, inner, 1.0f);
                float pv = __expf(x * poly);
                pv = (kvb + j < rowlim) ? pv : 0.f;
                if (j == 0) p0 = pv; else if (j == 1) p1 = pv;
                else if (j == 2) p2 = pv; else p3 = pv;
            }
            psA += p0 + p1;
            psB += p2 + p3;
            u32 pk0, pk1;
            asm("v_cvt_pk_bf16_f32 %0, %1, %2" : "=v"(pk0) : "v"(p0), "v"(p1));
            asm("v_cvt_pk_bf16_f32 %0, %1, %2" : "=v"(pk1) : "v"(p2), "v"(p3));
            *(u32*)&Pw[r * 72 + 16 * tt + 4 * g] = pk0;
            *(u32*)&Pw[r * 72 + 16 * tt + 4 * g + 2] = pk1;
        }
        short8 pf0 = *(const short8*)&Pw[r * 72 + 8 * g];
        short8 pf1 = *(const short8*)&Pw[r * 72 + 32 + 8 * g];
#pragma unroll
        for (int dt = 0; dt < 4; dt++) {
            int row = 16 * dt + r;
            short8 vf0 = *(const short8*)&Vt[(size_t)(row * 8 + (g ^ sw)) * 8];
            short8 vf1 = *(const short8*)&Vt[(size_t)(row * 8 + ((4 + g) ^ sw)) * 8];
            ot[dt] = __builtin_amdgcn_mfma_f32_16x16x32_bf16(vf0, pf0, ot[dt], 0, 0, 0);
            ot[dt] = __builtin_amdgcn_mfma_f32_16x16x32_bf16(vf1, pf1, ot[dt], 0, 0, 0);
        }
        asm volatile("s_waitcnt lgkmcnt(0)" ::: "memory");
        __builtin_amdgcn_s_barrier();
        buf ^= 1;
    }

    float lrow = psA + psB;
    lrow += __shfl_xor(lrow, 16);
    lrow += __shfl_xor(lrow, 32);
    float inv = 1.f / lrow;
    u16* Op = attn_out + ((size_t)(b * 2048 + qbase + r)) * 1024 + h * 64;
#pragma unroll
    for (int dt = 0; dt < 4; dt++) {
        u16x4 o = { f2bf(ot[dt][0] * inv), f2bf(ot[dt][1] * inv),
                    f2bf(ot[dt][2] * inv), f2bf(ot[dt][3] * inv) };
        *(u16x4*)(Op + dt * 16 + 4 * g) = o;
    }
}

extern "C" void kernel_launch(void* const* d_in, const int* in_sizes, int n_in,
                              void* d_out, int out_size, void* d_ws, size_t ws_size,
                              hipStream_t stream) {
    const float* x = (const float*)d_in[0];
    const float* gamma = (const float*)d_in[1];
    const float* w_qkv = (const float*)d_in[2];
    const float* w_out = (const float*)d_in[3];
    const int* mods = (const int*)d_in[4];
    float* out = (float*)d_out;

    u16* ws = (u16*)d_ws;
    u16* xn    = ws;                 // 4096*2048
    u16* wqkvT = ws + 8388608;       // 3072*2048
    u16* woutT = ws + 14680064;      // 2048*1024
    u16* qb    = ws + 16777216;      // 2*16*2048*64
    u16* kb    = ws + 20971520;
    u16* vT    = ws + 25165824;
    u16* ao    = ws + 29360128;      // 4096*1024

    transpose_cast<<<dim3(96, 64), dim3(32, 8), 0, stream>>>(w_qkv, wqkvT, 2048, 3072);
    transpose_cast<<<dim3(64, 32), dim3(32, 8), 0, stream>>>(w_out, woutT, 1024, 2048);
    rmsnorm_cast<<<dim3(4096), dim3(256), 0, stream>>>(x, gamma, xn);
    gemm8p<0><<<dim3(192), dim3(512), 0, stream>>>(xn, wqkvT, 4096, 3072, 2048, 12,
                                                   nullptr, qb, kb, vT);
    flash_attn<<<dim3(16, 2, 32), dim3(256), 0, stream>>>(qb, kb, vT, mods, ao);
    gemm8p<1><<<dim3(128), dim3(512), 0, stream>>>(ao, woutT, 4096, 2048, 1024, 8,
                                                   out, nullptr, nullptr, nullptr);
}

// Round 6
// 180.138 us; speedup vs baseline: 2.2571x; 1.0877x over previous
//
#include <hip/hip_runtime.h>
#include <hip/hip_bf16.h>

typedef unsigned short u16;
typedef unsigned int u32;
typedef __attribute__((ext_vector_type(8))) short short8;
typedef __attribute__((ext_vector_type(4))) float f32x4;
typedef __attribute__((ext_vector_type(4))) u16 u16x4;

#define DEV __device__ __forceinline__

DEV u16 f2bf(float f) {
    union { float f; u32 u; } v; v.f = f;
    u32 r = v.u;
    u32 lsb = (r >> 16) & 1u;
    r += 0x7fffu + lsb;
    return (u16)(r >> 16);
}

DEV void gload_lds16(const u16* g, u16* l) {
    __builtin_amdgcn_global_load_lds(
        (const __attribute__((address_space(1))) u32*)(const void*)g,
        (__attribute__((address_space(3))) u32*)(void*)l,
        16, 0, 0);
}

// ---------------- transpose + cast: in[R][C] fp32 -> out[C][R] bf16 ----------------
__global__ void transpose_cast(const float* __restrict__ in, u16* __restrict__ out,
                               int R, int C) {
    __shared__ float tile[32][33];
    int c0 = blockIdx.x * 32, r0 = blockIdx.y * 32;
    int tx = threadIdx.x, ty = threadIdx.y; // 32 x 8
#pragma unroll
    for (int i = 0; i < 4; i++)
        tile[ty * 4 + i][tx] = in[(size_t)(r0 + ty * 4 + i) * C + c0 + tx];
    __syncthreads();
#pragma unroll
    for (int i = 0; i < 4; i++)
        out[(size_t)(c0 + ty * 4 + i) * R + r0 + tx] = f2bf(tile[tx][ty * 4 + i]);
}

// ---------------- RMSNorm + cast to bf16: x[4096][2048] -> xn ----------------
__global__ void rmsnorm_cast(const float* __restrict__ x, const float* __restrict__ gamma,
                             u16* __restrict__ xn) {
    int row = blockIdx.x;
    int t = threadIdx.x; // 256
    const float4* xr = (const float4*)(x + (size_t)row * 2048);
    float4 a = xr[t];
    float4 b = xr[256 + t];
    float ss = a.x * a.x + a.y * a.y + a.z * a.z + a.w * a.w +
               b.x * b.x + b.y * b.y + b.z * b.z + b.w * b.w;
#pragma unroll
    for (int off = 32; off; off >>= 1) ss += __shfl_xor(ss, off);
    __shared__ float red[4];
    if ((t & 63) == 0) red[t >> 6] = ss;
    __syncthreads();
    float tot = red[0] + red[1] + red[2] + red[3];
    float n = sqrtf(tot);
    float inv = 45.254833995939045f / fmaxf(n, 1e-12f); // sqrt(2048)/max(n,eps)
    const float4* gr = (const float4*)gamma;
    float4 g0 = gr[t], g1 = gr[256 + t];
    u16x4 o0 = { f2bf(a.x * inv * (g0.x + 1.f)), f2bf(a.y * inv * (g0.y + 1.f)),
                 f2bf(a.z * inv * (g0.z + 1.f)), f2bf(a.w * inv * (g0.w + 1.f)) };
    u16x4 o1 = { f2bf(b.x * inv * (g1.x + 1.f)), f2bf(b.y * inv * (g1.y + 1.f)),
                 f2bf(b.z * inv * (g1.z + 1.f)), f2bf(b.w * inv * (g1.w + 1.f)) };
    u16x4* xo = (u16x4*)(xn + (size_t)row * 2048);
    xo[t] = o0;
    xo[256 + t] = o1;
}

// ---------------- 256xBN 8-phase GEMM: C = A[M,K] @ BT[N,K]^T ----------------
// 512 threads = 8 waves (WM x WN); BM=256, BN=WN*64, BK=64 in 2 K-halves.
// LDS slots: [buf][kh] 256(or BN) rows x 32 k-elems, 64B row stride.
// Bank swizzle (both sides): 16B chunk' = chunk ^ ((row>>1)&3); staged with
// linear LDS dest + pre-swizzled GLOBAL source (gk), read with lin = g^((r>>1)&3)
// -> rows base..base+15 cover all 8 bank-quads twice = b128 floor, 0 conflicts.
// Per K-tile: 4 phases {ds_read frags | stage 1 half-tile -> barrier ->
// lgkmcnt(0) -> setprio(1) -> MFMA -> setprio(0) -> barrier}; boundary
// vmcnt(2+BLB) keeps next-next kh0 in flight (never 0 mid-loop).
template <int EPI, int WM, int WN>
__global__ __launch_bounds__(512, 1) void gemm8p(
    const u16* __restrict__ A, const u16* __restrict__ BT,
    int M, int N, int K, int nbx,
    float* __restrict__ Cout,
    u16* __restrict__ qb, u16* __restrict__ kb, u16* __restrict__ vT) {
    constexpr int MF = 16 / WM;       // m-fragments per wave
    constexpr int BN = WN * 64;
    constexpr int BLB = BN / 128;     // B gloads per thread per half (1 or 2)
    __shared__ __align__(16) u16 As[2][2][8192];
    __shared__ __align__(16) u16 Bs[2][2][BN * 32];
    int t = threadIdx.x, lane = t & 63, wid = t >> 6;
    int g = lane >> 4, r = lane & 15;
    int wm = wid / WN, wn = wid % WN;
    int lin = (g ^ ((r >> 1) & 3)) * 8; // swizzled chunk offset (u16) for reads

    int nwg = gridDim.x;
    int id = blockIdx.x;
    int wg = (id & 7) * (nwg >> 3) + (id >> 3); // XCD swizzle (nwg % 8 == 0)
    int bx = wg % nbx, by = wg / nbx;
    int brow = by * 256, bcol = bx * BN;

    // staging: chunk c = i*512 + t -> row = c>>2, linpos = t&3; source chunk
    // gk = linpos ^ ((row>>1)&3) (identical for both row-halves: 128 % 8 == 0)
    int gk = (t & 3) ^ ((t >> 3) & 3);
    const u16* Ag = A + (size_t)(brow + (t >> 2)) * K + gk * 8;
    const u16* Bg = BT + (size_t)(bcol + (t >> 2)) * K + gk * 8;
    const size_t rstep = (size_t)128 * K;
    int dst0 = (t & ~63) * 8;
    int dst1 = 4096 + dst0;

    f32x4 acc[MF][4] = {};
    int NT = K >> 6;

#define STG_A(bf_, kt_, kh_) { \
        gload_lds16(Ag + (kt_) * 64 + (kh_) * 32,         &As[bf_][kh_][dst0]); \
        gload_lds16(Ag + rstep + (kt_) * 64 + (kh_) * 32, &As[bf_][kh_][dst1]); }
#define STG_B(bf_, kt_, kh_) { \
        gload_lds16(Bg + (kt_) * 64 + (kh_) * 32, &Bs[bf_][kh_][dst0]); \
        if constexpr (BLB == 2) \
            gload_lds16(Bg + rstep + (kt_) * 64 + (kh_) * 32, &Bs[bf_][kh_][dst1]); }
#define WAIT_INFLIGHT() { \
        if constexpr (BLB == 2) { asm volatile("s_waitcnt vmcnt(4)" ::: "memory"); } \
        else                    { asm volatile("s_waitcnt vmcnt(3)" ::: "memory"); } }

    // prologue: T0 complete + T1 kh0; leave T1 kh0 in flight
    STG_A(0, 0, 0); STG_B(0, 0, 0);
    STG_A(0, 0, 1); STG_B(0, 0, 1);
    STG_A(1, 1, 0); STG_B(1, 1, 0);
    WAIT_INFLIGHT();
    __builtin_amdgcn_s_barrier();

    for (int kt = 0; kt < NT; ++kt) {
        int buf = kt & 1, ob = buf ^ 1;
        const u16* Ak0 = As[buf][0];
        const u16* Ak1 = As[buf][1];
        const u16* Bk0 = Bs[buf][0];
        const u16* Bk1 = Bs[buf][1];
        bool s1 = kt + 1 < NT, s2 = kt + 2 < NT;
        short8 af[MF / 2], bfr[4];

        // ---- phase 0: kh0, m-half 0 ----
#pragma unroll
        for (int n = 0; n < 4; n++)
            bfr[n] = *(const short8*)&Bk0[(wn * 64 + n * 16 + r) * 32 + lin];
#pragma unroll
        for (int m = 0; m < MF / 2; m++)
            af[m] = *(const short8*)&Ak0[(wm * (MF * 16) + m * 16 + r) * 32 + lin];
        if (s1) STG_A(ob, kt + 1, 1);
        __builtin_amdgcn_s_barrier();
        asm volatile("s_waitcnt lgkmcnt(0)" ::: "memory");
        __builtin_amdgcn_s_setprio(1);
#pragma unroll
        for (int m = 0; m < MF / 2; m++)
#pragma unroll
            for (int n = 0; n < 4; n++)
                acc[m][n] = __builtin_amdgcn_mfma_f32_16x16x32_bf16(af[m], bfr[n], acc[m][n], 0, 0, 0);
        __builtin_amdgcn_s_setprio(0);
        __builtin_amdgcn_s_barrier();

        // ---- phase 1: kh0, m-half 1 ----
#pragma unroll
        for (int m = 0; m < MF / 2; m++)
            af[m] = *(const short8*)&Ak0[(wm * (MF * 16) + (MF / 2) * 16 + m * 16 + r) * 32 + lin];
        if (s1) STG_B(ob, kt + 1, 1);
        __builtin_amdgcn_s_barrier();
        asm volatile("s_waitcnt lgkmcnt(0)" ::: "memory");
        __builtin_amdgcn_s_setprio(1);
#pragma unroll
        for (int m = 0; m < MF / 2; m++)
#pragma unroll
            for (int n = 0; n < 4; n++)
                acc[MF / 2 + m][n] = __builtin_amdgcn_mfma_f32_16x16x32_bf16(af[m], bfr[n], acc[MF / 2 + m][n], 0, 0, 0);
        __builtin_amdgcn_s_setprio(0);
        __builtin_amdgcn_s_barrier();

        // ---- phase 2: kh1, m-half 0 (this buf's kh0 retired -> stage kt+2 kh0) ----
#pragma unroll
        for (int n = 0; n < 4; n++)
            bfr[n] = *(const short8*)&Bk1[(wn * 64 + n * 16 + r) * 32 + lin];
#pragma unroll
        for (int m = 0; m < MF / 2; m++)
            af[m] = *(const short8*)&Ak1[(wm * (MF * 16) + m * 16 + r) * 32 + lin];
        if (s2) STG_A(buf, kt + 2, 0);
        __builtin_amdgcn_s_barrier();
        asm volatile("s_waitcnt lgkmcnt(0)" ::: "memory");
        __builtin_amdgcn_s_setprio(1);
#pragma unroll
        for (int m = 0; m < MF / 2; m++)
#pragma unroll
            for (int n = 0; n < 4; n++)
                acc[m][n] = __builtin_amdgcn_mfma_f32_16x16x32_bf16(af[m], bfr[n], acc[m][n], 0, 0, 0);
        __builtin_amdgcn_s_setprio(0);
        __builtin_amdgcn_s_barrier();

        // ---- phase 3: kh1, m-half 1 ----
#pragma unroll
        for (int m = 0; m < MF / 2; m++)
            af[m] = *(const short8*)&Ak1[(wm * (MF * 16) + (MF / 2) * 16 + m * 16 + r) * 32 + lin];
        if (s2) STG_B(buf, kt + 2, 0);
        __builtin_amdgcn_s_barrier();
        asm volatile("s_waitcnt lgkmcnt(0)" ::: "memory");
        __builtin_amdgcn_s_setprio(1);
#pragma unroll
        for (int m = 0; m < MF / 2; m++)
#pragma unroll
            for (int n = 0; n < 4; n++)
                acc[MF / 2 + m][n] = __builtin_amdgcn_mfma_f32_16x16x32_bf16(af[m], bfr[n], acc[MF / 2 + m][n], 0, 0, 0);
        __builtin_amdgcn_s_setprio(0);
        // boundary: T(kt+1) fully landed; keep T(kt+2) kh0 in flight
        if (s2)      { WAIT_INFLIGHT(); }
        else if (s1) { asm volatile("s_waitcnt vmcnt(0)" ::: "memory"); }
        __builtin_amdgcn_s_barrier();
    }
#undef STG_A
#undef STG_B
#undef WAIT_INFLIGHT

    if (EPI == 0) {
#pragma unroll
        for (int m = 0; m < MF; m++)
#pragma unroll
            for (int n = 0; n < 4; n++) {
                int cb = bcol + wn * 64 + n * 16 + r;
                int which = cb >> 10;
                int hd = cb & 1023;
                int hh = hd >> 6, d = hd & 63;
#pragma unroll
                for (int j = 0; j < 4; j++) {
                    int rr = brow + wm * (MF * 16) + m * 16 + 4 * g + j;
                    int b = rr >> 11, nn = rr & 2047;
                    float v = acc[m][n][j];
                    size_t bh = (size_t)(b * 16 + hh);
                    if (which == 0)      qb[(bh * 2048 + nn) * 64 + d] = f2bf(v * 0.125f);
                    else if (which == 1) kb[(bh * 2048 + nn) * 64 + d] = f2bf(v);
                    else                 vT[(bh * 64 + d) * 2048 + nn] = f2bf(v);
                }
            }
    } else {
#pragma unroll
        for (int m = 0; m < MF; m++)
#pragma unroll
            for (int n = 0; n < 4; n++) {
                int cb = bcol + wn * 64 + n * 16 + r;
#pragma unroll
                for (int j = 0; j < 4; j++) {
                    int rr = brow + wm * (MF * 16) + m * 16 + 4 * g + j;
                    Cout[(size_t)rr * N + cb] = acc[m][n][j];
                }
            }
    }
}

// ---------------- flash attention v3: block-shared LDS K/V, double-buffered ----------------
__global__ __launch_bounds__(256, 3) void flash_attn(
    const u16* __restrict__ q, const u16* __restrict__ kk, const u16* __restrict__ vT,
    const int* __restrict__ mods, u16* __restrict__ attn_out) {
    __shared__ __align__(16) u16 Ks[2][4096];
    __shared__ __align__(16) u16 Vs[2][4096];
    __shared__ __align__(16) u16 Plds[4][16][72];
    int t = threadIdx.x, lane = t & 63, wave = t >> 6;
    int g = lane >> 4, r = lane & 15;
    int h = blockIdx.x, b = blockIdx.y;
    int qs = (31 - blockIdx.z) * 64;          // longest q-blocks dispatched first
    int bh = b * 16 + h;
    int qbase = qs + wave * 16;

    int off0 = mods[b * 6 + 1], end0 = off0 + mods[b * 6 + 2];
    int off1 = mods[b * 6 + 4], end1 = off1 + mods[b * 6 + 5];

    const u16* Qp = q + ((size_t)bh * 2048 + qbase) * 64;
    short8 qf0 = *(const short8*)(Qp + (size_t)r * 64 + 8 * g);
    short8 qf1 = *(const short8*)(Qp + (size_t)r * 64 + 32 + 8 * g);

    int iq = qbase + r;
    int lim0 = (iq >= off0) ? end0 : 0;
    int lim1 = (iq >= off1) ? end1 : 0;
    int rowlim = max(iq + 1, max(lim0, lim1));

    int jlb = qs + 64;
    if (qs + 63 >= off0) jlb = max(jlb, end0);
    if (qs + 63 >= off1) jlb = max(jlb, end1);

    const u16* Kp = kk + (size_t)bh * 2048 * 64;
    const u16* Vp = vT + (size_t)bh * 64 * 2048;
    u16* Pw = &Plds[wave][0][0];

    f32x4 ot[4] = {};
    float psA = 0.f, psB = 0.f;
    int sw = r & 7;

    auto stage64 = [&](const u16* gbase, int gstride, u16* lds) {
#pragma unroll
        for (int i = 0; i < 2; i++) {
            int c = i * 256 + t;
            int row = c >> 3;
            int gsl = (c & 7) ^ (row & 7);
            gload_lds16(gbase + (size_t)row * gstride + 8 * gsl,
                        lds + (size_t)(c & ~63) * 8);
        }
    };

    stage64(Kp, 64, Ks[0]);
    stage64(Vp, 2048, Vs[0]);
    int buf = 0;

    for (int jb = 0; jb < jlb; jb += 64) {
        if (jb + 64 < jlb) {
            stage64(Kp + (size_t)(jb + 64) * 64, 64, Ks[buf ^ 1]);
            stage64(Vp + (jb + 64), 2048, Vs[buf ^ 1]);
            asm volatile("s_waitcnt vmcnt(4)" ::: "memory");
        } else {
            asm volatile("s_waitcnt vmcnt(0)" ::: "memory");
        }
        __builtin_amdgcn_s_barrier();
        const u16* Kt = Ks[buf];
        const u16* Vt = Vs[buf];

        f32x4 st[4];
#pragma unroll
        for (int tt = 0; tt < 4; tt++) {
            int row = 16 * tt + r;
            short8 kf0 = *(const short8*)&Kt[(size_t)(row * 8 + (g ^ sw)) * 8];
            short8 kf1 = *(const short8*)&Kt[(size_t)(row * 8 + ((4 + g) ^ sw)) * 8];
            f32x4 z = {};
            z = __builtin_amdgcn_mfma_f32_16x16x32_bf16(kf0, qf0, z, 0, 0, 0);
            z = __builtin_amdgcn_mfma_f32_16x16x32_bf16(kf1, qf1, z, 0, 0, 0);
            st[tt] = z;
        }
#pragma unroll
        for (int tt = 0; tt < 4; tt++) {
            int kvb = jb + 16 * tt + 4 * g;
            float p0, p1, p2, p3;
#pragma unroll
            for (int j = 0; j < 4; j++) {
                float x = st[tt][j];
                float x2 = x * x;
                float inner = __builtin_fmaf(x2, 2.1333333e-8f, -1.3333333e-4f);
                float poly = __builtin_fmaf(x2, inner, 1.0f);
                float pv = __expf(x * poly);
                pv = (kvb + j < rowlim) ? pv : 0.f;
                if (j == 0) p0 = pv; else if (j == 1) p1 = pv;
                else if (j == 2) p2 = pv; else p3 = pv;
            }
            psA += p0 + p1;
            psB += p2 + p3;
            u32 pk0, pk1;
            asm("v_cvt_pk_bf16_f32 %0, %1, %2" : "=v"(pk0) : "v"(p0), "v"(p1));
            asm("v_cvt_pk_bf16_f32 %0, %1, %2" : "=v"(pk1) : "v"(p2), "v"(p3));
            *(u32*)&Pw[r * 72 + 16 * tt + 4 * g] = pk0;
            *(u32*)&Pw[r * 72 + 16 * tt + 4 * g + 2] = pk1;
        }
        short8 pf0 = *(const short8*)&Pw[r * 72 + 8 * g];
        short8 pf1 = *(const short8*)&Pw[r * 72 + 32 + 8 * g];
#pragma unroll
        for (int dt = 0; dt < 4; dt++) {
            int row = 16 * dt + r;
            short8 vf0 = *(const short8*)&Vt[(size_t)(row * 8 + (g ^ sw)) * 8];
            short8 vf1 = *(const short8*)&Vt[(size_t)(row * 8 + ((4 + g) ^ sw)) * 8];
            ot[dt] = __builtin_amdgcn_mfma_f32_16x16x32_bf16(vf0, pf0, ot[dt], 0, 0, 0);
            ot[dt] = __builtin_amdgcn_mfma_f32_16x16x32_bf16(vf1, pf1, ot[dt], 0, 0, 0);
        }
        asm volatile("s_waitcnt lgkmcnt(0)" ::: "memory");
        __builtin_amdgcn_s_barrier();
        buf ^= 1;
    }

    float lrow = psA + psB;
    lrow += __shfl_xor(lrow, 16);
    lrow += __shfl_xor(lrow, 32);
    float inv = 1.f / lrow;
    u16* Op = attn_out + ((size_t)(b * 2048 + qbase + r)) * 1024 + h * 64;
#pragma unroll
    for (int dt = 0; dt < 4; dt++) {
        u16x4 o = { f2bf(ot[dt][0] * inv), f2bf(ot[dt][1] * inv),
                    f2bf(ot[dt][2] * inv), f2bf(ot[dt][3] * inv) };
        *(u16x4*)(Op + dt * 16 + 4 * g) = o;
    }
}

extern "C" void kernel_launch(void* const* d_in, const int* in_sizes, int n_in,
                              void* d_out, int out_size, void* d_ws, size_t ws_size,
                              hipStream_t stream) {
    const float* x = (const float*)d_in[0];
    const float* gamma = (const float*)d_in[1];
    const float* w_qkv = (const float*)d_in[2];
    const float* w_out = (const float*)d_in[3];
    const int* mods = (const int*)d_in[4];
    float* out = (float*)d_out;

    u16* ws = (u16*)d_ws;
    u16* xn    = ws;                 // 4096*2048
    u16* wqkvT = ws + 8388608;       // 3072*2048
    u16* woutT = ws + 14680064;      // 2048*1024
    u16* qb    = ws + 16777216;      // 2*16*2048*64
    u16* kb    = ws + 20971520;
    u16* vT    = ws + 25165824;
    u16* ao    = ws + 29360128;      // 4096*1024

    transpose_cast<<<dim3(96, 64), dim3(32, 8), 0, stream>>>(w_qkv, wqkvT, 2048, 3072);
    transpose_cast<<<dim3(64, 32), dim3(32, 8), 0, stream>>>(w_out, woutT, 1024, 2048);
    rmsnorm_cast<<<dim3(4096), dim3(256), 0, stream>>>(x, gamma, xn);
    gemm8p<0, 2, 4><<<dim3(192), dim3(512), 0, stream>>>(xn, wqkvT, 4096, 3072, 2048, 12,
                                                         nullptr, qb, kb, vT);
    flash_attn<<<dim3(16, 2, 32), dim3(256), 0, stream>>>(qb, kb, vT, mods, ao);
    gemm8p<1, 4, 2><<<dim3(256), dim3(512), 0, stream>>>(ao, woutT, 4096, 2048, 1024, 16,
                                                         out, nullptr, nullptr, nullptr);
}

// Round 7
// 177.252 us; speedup vs baseline: 2.2938x; 1.0163x over previous
//
#include <hip/hip_runtime.h>
#include <hip/hip_bf16.h>

typedef unsigned short u16;
typedef unsigned int u32;
typedef __attribute__((ext_vector_type(8))) short short8;
typedef __attribute__((ext_vector_type(4))) float f32x4;
typedef __attribute__((ext_vector_type(16))) float f32x16;
typedef __attribute__((ext_vector_type(4))) u16 u16x4;

#define DEV __device__ __forceinline__

DEV u16 f2bf(float f) {
    union { float f; u32 u; } v; v.f = f;
    u32 r = v.u;
    u32 lsb = (r >> 16) & 1u;
    r += 0x7fffu + lsb;
    return (u16)(r >> 16);
}

DEV void gload_lds16(const u16* g, u16* l) {
    __builtin_amdgcn_global_load_lds(
        (const __attribute__((address_space(1))) u32*)(const void*)g,
        (__attribute__((address_space(3))) u32*)(void*)l,
        16, 0, 0);
}

// ---------------- merged prep: two weight transposes + RMSNorm, one launch ----------------
__global__ void prep(const float* __restrict__ x, const float* __restrict__ gamma,
                     const float* __restrict__ w_qkv, const float* __restrict__ w_out,
                     u16* __restrict__ xn, u16* __restrict__ wqkvT, u16* __restrict__ woutT) {
    __shared__ float tile[32][33];
    __shared__ float red[4];
    int id = blockIdx.x;
    int t = threadIdx.x;
    if (id < 8192) {
        const float* in; u16* out; int R, C, bx, by;
        if (id < 6144) { in = w_qkv; out = wqkvT; R = 2048; C = 3072; bx = id % 96; by = id / 96; }
        else { id -= 6144; in = w_out; out = woutT; R = 1024; C = 2048; bx = id % 64; by = id / 64; }
        int tx = t & 31, ty = t >> 5;
        int c0 = bx * 32, r0 = by * 32;
#pragma unroll
        for (int i = 0; i < 4; i++)
            tile[ty * 4 + i][tx] = in[(size_t)(r0 + ty * 4 + i) * C + c0 + tx];
        __syncthreads();
#pragma unroll
        for (int i = 0; i < 4; i++)
            out[(size_t)(c0 + ty * 4 + i) * R + r0 + tx] = f2bf(tile[tx][ty * 4 + i]);
    } else {
        int row = id - 8192;
        const float4* xr = (const float4*)(x + (size_t)row * 2048);
        float4 a = xr[t];
        float4 b = xr[256 + t];
        float ss = a.x * a.x + a.y * a.y + a.z * a.z + a.w * a.w +
                   b.x * b.x + b.y * b.y + b.z * b.z + b.w * b.w;
#pragma unroll
        for (int off = 32; off; off >>= 1) ss += __shfl_xor(ss, off);
        if ((t & 63) == 0) red[t >> 6] = ss;
        __syncthreads();
        float tot = red[0] + red[1] + red[2] + red[3];
        float n = sqrtf(tot);
        float inv = 45.254833995939045f / fmaxf(n, 1e-12f);
        const float4* gr = (const float4*)gamma;
        float4 g0 = gr[t], g1 = gr[256 + t];
        u16x4 o0 = { f2bf(a.x * inv * (g0.x + 1.f)), f2bf(a.y * inv * (g0.y + 1.f)),
                     f2bf(a.z * inv * (g0.z + 1.f)), f2bf(a.w * inv * (g0.w + 1.f)) };
        u16x4 o1 = { f2bf(b.x * inv * (g1.x + 1.f)), f2bf(b.y * inv * (g1.y + 1.f)),
                     f2bf(b.z * inv * (g1.z + 1.f)), f2bf(b.w * inv * (g1.w + 1.f)) };
        u16x4* xo = (u16x4*)(xn + (size_t)row * 2048);
        xo[t] = o0;
        xo[256 + t] = o1;
    }
}

// ---------------- 256xBN GEMM, 32x32x16 MFMA, 2 phases/K-tile ----------------
// 512 threads = 8 waves (WM x WN); BM=256, BN=WN*64, BK=64 (2 K-halves).
// LDS [buf][kh]: rows x 32 k-elems, 64B row stride; 16B-chunk swizzle
// chunk' = chunk ^ ((row>>1)&3) both sides (stage: pre-swizzled global src,
// read: lane swizzle sw=(l31>>1)&3) -> 8 lanes/bank-quad uniform, 0 conflicts.
// Phase = {ds_read 8-12 b128 | stage 1 K-half | lgkmcnt(0) | setprio | MFMA
// cluster | setprio | [boundary vmcnt] | barrier}. lgkm precedes barrier =>
// all reads complete at barrier => next phase may overwrite retired slots.
// 2-D XCD chunk: xcd = id&7 -> 4-row x CCOL-col sub-grid (L2 working set).
template <int EPI, int WM, int WN, int CCOL>
__global__ __launch_bounds__(512, 1) void gemm32(
    const u16* __restrict__ A, const u16* __restrict__ BT,
    int M, int N, int K,
    float* __restrict__ Cout,
    u16* __restrict__ qb, u16* __restrict__ kb, u16* __restrict__ vT) {
    constexpr int MFR = 256 / (WM * 32);  // 32-row m-frags per wave
    constexpr int BN = WN * 64;
    constexpr int BLB = BN / 128;         // B gloads per thread per K-half
    __shared__ __align__(16) u16 As[2][2][8192];
    __shared__ __align__(16) u16 Bs[2][2][BN * 32];
    int t = threadIdx.x, lane = t & 63, wid = t >> 6;
    int l31 = lane & 31, hi = lane >> 5;
    int sw = (l31 >> 1) & 3;
    int wm = wid / WN, wn = wid % WN;

    int id = blockIdx.x;
    int xcd = id & 7, slot = id >> 3;
    int by = (xcd >> 1) * 4 + slot / CCOL;
    int bx = (xcd & 1) * CCOL + slot % CCOL;
    int brow = by * 256, bcol = bx * BN;

    // staging: chunk c = i*512+t -> row = i*128 + (t>>2); source chunk
    // gk = (t&3) ^ ((row>>1)&3) = (t&3) ^ ((t>>3)&3)  (i*128 ≡ 0 mod 8)
    int gk = (t & 3) ^ ((t >> 3) & 3);
    const u16* Ag = A + (size_t)(brow + (t >> 2)) * K + gk * 8;
    const u16* Bg = BT + (size_t)(bcol + (t >> 2)) * K + gk * 8;
    const size_t rstep = (size_t)128 * K;
    int dst0 = (t & ~63) * 8;
    int dst1 = 4096 + dst0;

    f32x16 acc[MFR][2] = {};
    int NT = K >> 6;

#define STG_A(bf_, kt_, kh_) { \
        gload_lds16(Ag + (kt_) * 64 + (kh_) * 32,         &As[bf_][kh_][dst0]); \
        gload_lds16(Ag + rstep + (kt_) * 64 + (kh_) * 32, &As[bf_][kh_][dst1]); }
#define STG_B(bf_, kt_, kh_) { \
        gload_lds16(Bg + (kt_) * 64 + (kh_) * 32, &Bs[bf_][kh_][dst0]); \
        if constexpr (BLB == 2) \
            gload_lds16(Bg + rstep + (kt_) * 64 + (kh_) * 32, &Bs[bf_][kh_][dst1]); }
#define WAIT_INFLIGHT() { \
        if constexpr (BLB == 2) { asm volatile("s_waitcnt vmcnt(4)" ::: "memory"); } \
        else                    { asm volatile("s_waitcnt vmcnt(3)" ::: "memory"); } }

    // prologue: T0 kh0+kh1, T1 kh0; leave T1 kh0 in flight
    STG_A(0, 0, 0); STG_B(0, 0, 0);
    STG_A(0, 0, 1); STG_B(0, 0, 1);
    STG_A(1, 1, 0); STG_B(1, 1, 0);
    WAIT_INFLIGHT();
    __builtin_amdgcn_s_barrier();

    for (int kt = 0; kt < NT; ++kt) {
        int buf = kt & 1, ob = buf ^ 1;
        const u16* Ak0 = As[buf][0];
        const u16* Ak1 = As[buf][1];
        const u16* Bk0 = Bs[buf][0];
        const u16* Bk1 = Bs[buf][1];
        bool s1 = kt + 1 < NT, s2 = kt + 2 < NT;
        short8 af[MFR][2], bfr[2][2];

        // ---- phase 0: k-half 0 (kf 0,1) ----
#pragma unroll
        for (int nf = 0; nf < 2; nf++)
#pragma unroll
            for (int kf = 0; kf < 2; kf++)
                bfr[nf][kf] = *(const short8*)&Bk0[(wn * 64 + nf * 32 + l31) * 32 + ((kf * 2 + hi) ^ sw) * 8];
#pragma unroll
        for (int mf = 0; mf < MFR; mf++)
#pragma unroll
            for (int kf = 0; kf < 2; kf++)
                af[mf][kf] = *(const short8*)&Ak0[(wm * (MFR * 32) + mf * 32 + l31) * 32 + ((kf * 2 + hi) ^ sw) * 8];
        if (s1) { STG_A(ob, kt + 1, 1); STG_B(ob, kt + 1, 1); }
        asm volatile("s_waitcnt lgkmcnt(0)" ::: "memory");
        __builtin_amdgcn_s_setprio(1);
#pragma unroll
        for (int kf = 0; kf < 2; kf++)
#pragma unroll
            for (int mf = 0; mf < MFR; mf++)
#pragma unroll
                for (int nf = 0; nf < 2; nf++)
                    acc[mf][nf] = __builtin_amdgcn_mfma_f32_32x32x16_bf16(af[mf][kf], bfr[nf][kf], acc[mf][nf], 0, 0, 0);
        __builtin_amdgcn_s_setprio(0);
        __builtin_amdgcn_s_barrier();

        // ---- phase 1: k-half 1 (kf 2,3); stage kt+2 kh0 (retired in phase 0) ----
#pragma unroll
        for (int nf = 0; nf < 2; nf++)
#pragma unroll
            for (int kf = 0; kf < 2; kf++)
                bfr[nf][kf] = *(const short8*)&Bk1[(wn * 64 + nf * 32 + l31) * 32 + ((kf * 2 + hi) ^ sw) * 8];
#pragma unroll
        for (int mf = 0; mf < MFR; mf++)
#pragma unroll
            for (int kf = 0; kf < 2; kf++)
                af[mf][kf] = *(const short8*)&Ak1[(wm * (MFR * 32) + mf * 32 + l31) * 32 + ((kf * 2 + hi) ^ sw) * 8];
        if (s2) { STG_A(buf, kt + 2, 0); STG_B(buf, kt + 2, 0); }
        asm volatile("s_waitcnt lgkmcnt(0)" ::: "memory");
        __builtin_amdgcn_s_setprio(1);
#pragma unroll
        for (int kf = 0; kf < 2; kf++)
#pragma unroll
            for (int mf = 0; mf < MFR; mf++)
#pragma unroll
                for (int nf = 0; nf < 2; nf++)
                    acc[mf][nf] = __builtin_amdgcn_mfma_f32_32x32x16_bf16(af[mf][kf], bfr[nf][kf], acc[mf][nf], 0, 0, 0);
        __builtin_amdgcn_s_setprio(0);
        if (s2)      { WAIT_INFLIGHT(); }
        else if (s1) { asm volatile("s_waitcnt vmcnt(0)" ::: "memory"); }
        __builtin_amdgcn_s_barrier();
    }
#undef STG_A
#undef STG_B
#undef WAIT_INFLIGHT

    // C/D 32x32: col = l31, row = (reg&3) + 8*(reg>>2) + 4*hi
    if (EPI == 0) {
#pragma unroll
        for (int mf = 0; mf < MFR; mf++)
#pragma unroll
            for (int nf = 0; nf < 2; nf++) {
                int cb = bcol + wn * 64 + nf * 32 + l31;
                int which = cb >> 10;
                int hd = cb & 1023;
                int hh = hd >> 6, d = hd & 63;
#pragma unroll
                for (int reg = 0; reg < 16; reg++) {
                    int rr = brow + wm * (MFR * 32) + mf * 32 + (reg & 3) + 8 * (reg >> 2) + 4 * hi;
                    int b = rr >> 11, nn = rr & 2047;
                    float v = acc[mf][nf][reg];
                    size_t bh = (size_t)(b * 16 + hh);
                    if (which == 0)      qb[(bh * 2048 + nn) * 64 + d] = f2bf(v * 0.125f);
                    else if (which == 1) kb[(bh * 2048 + nn) * 64 + d] = f2bf(v);
                    else                 vT[(bh * 64 + d) * 2048 + nn] = f2bf(v);
                }
            }
    } else {
#pragma unroll
        for (int mf = 0; mf < MFR; mf++)
#pragma unroll
            for (int nf = 0; nf < 2; nf++) {
                int cb = bcol + wn * 64 + nf * 32 + l31;
#pragma unroll
                for (int reg = 0; reg < 16; reg++) {
                    int rr = brow + wm * (MFR * 32) + mf * 32 + (reg & 3) + 8 * (reg >> 2) + 4 * hi;
                    Cout[(size_t)rr * N + cb] = acc[mf][nf][reg];
                }
            }
    }
}

// ---------------- flash attention v3: block-shared LDS K/V, double-buffered ----------------
__global__ __launch_bounds__(256, 3) void flash_attn(
    const u16* __restrict__ q, const u16* __restrict__ kk, const u16* __restrict__ vT,
    const int* __restrict__ mods, u16* __restrict__ attn_out) {
    __shared__ __align__(16) u16 Ks[2][4096];
    __shared__ __align__(16) u16 Vs[2][4096];
    __shared__ __align__(16) u16 Plds[4][16][72];
    int t = threadIdx.x, lane = t & 63, wave = t >> 6;
    int g = lane >> 4, r = lane & 15;
    int h = blockIdx.x, b = blockIdx.y;
    int qs = (31 - blockIdx.z) * 64;          // longest q-blocks dispatched first
    int bh = b * 16 + h;
    int qbase = qs + wave * 16;

    int off0 = mods[b * 6 + 1], end0 = off0 + mods[b * 6 + 2];
    int off1 = mods[b * 6 + 4], end1 = off1 + mods[b * 6 + 5];

    const u16* Qp = q + ((size_t)bh * 2048 + qbase) * 64;
    short8 qf0 = *(const short8*)(Qp + (size_t)r * 64 + 8 * g);
    short8 qf1 = *(const short8*)(Qp + (size_t)r * 64 + 32 + 8 * g);

    int iq = qbase + r;
    int lim0 = (iq >= off0) ? end0 : 0;
    int lim1 = (iq >= off1) ? end1 : 0;
    int rowlim = max(iq + 1, max(lim0, lim1));

    int jlb = qs + 64;
    if (qs + 63 >= off0) jlb = max(jlb, end0);
    if (qs + 63 >= off1) jlb = max(jlb, end1);

    const u16* Kp = kk + (size_t)bh * 2048 * 64;
    const u16* Vp = vT + (size_t)bh * 64 * 2048;
    u16* Pw = &Plds[wave][0][0];

    f32x4 ot[4] = {};
    float psA = 0.f, psB = 0.f;
    int sw = r & 7;

    auto stage64 = [&](const u16* gbase, int gstride, u16* lds) {
#pragma unroll
        for (int i = 0; i < 2; i++) {
            int c = i * 256 + t;
            int row = c >> 3;
            int gsl = (c & 7) ^ (row & 7);
            gload_lds16(gbase + (size_t)row * gstride + 8 * gsl,
                        lds + (size_t)(c & ~63) * 8);
        }
    };

    stage64(Kp, 64, Ks[0]);
    stage64(Vp, 2048, Vs[0]);
    int buf = 0;

    for (int jb = 0; jb < jlb; jb += 64) {
        if (jb + 64 < jlb) {
            stage64(Kp + (size_t)(jb + 64) * 64, 64, Ks[buf ^ 1]);
            stage64(Vp + (jb + 64), 2048, Vs[buf ^ 1]);
            asm volatile("s_waitcnt vmcnt(4)" ::: "memory");
        } else {
            asm volatile("s_waitcnt vmcnt(0)" ::: "memory");
        }
        __builtin_amdgcn_s_barrier();
        const u16* Kt = Ks[buf];
        const u16* Vt = Vs[buf];

        f32x4 st[4];
#pragma unroll
        for (int tt = 0; tt < 4; tt++) {
            int row = 16 * tt + r;
            short8 kf0 = *(const short8*)&Kt[(size_t)(row * 8 + (g ^ sw)) * 8];
            short8 kf1 = *(const short8*)&Kt[(size_t)(row * 8 + ((4 + g) ^ sw)) * 8];
            f32x4 z = {};
            z = __builtin_amdgcn_mfma_f32_16x16x32_bf16(kf0, qf0, z, 0, 0, 0);
            z = __builtin_amdgcn_mfma_f32_16x16x32_bf16(kf1, qf1, z, 0, 0, 0);
            st[tt] = z;
        }
#pragma unroll
        for (int tt = 0; tt < 4; tt++) {
            int kvb = jb + 16 * tt + 4 * g;
            float p0, p1, p2, p3;
#pragma unroll
            for (int j = 0; j < 4; j++) {
                float x = st[tt][j];
                float x2 = x * x;
                float inner = __builtin_fmaf(x2, 2.1333333e-8f, -1.3333333e-4f);
                float poly = __builtin_fmaf(x2, inner, 1.0f);
                float pv = __expf(x * poly);
                pv = (kvb + j < rowlim) ? pv : 0.f;
                if (j == 0) p0 = pv; else if (j == 1) p1 = pv;
                else if (j == 2) p2 = pv; else p3 = pv;
            }
            psA += p0 + p1;
            psB += p2 + p3;
            u32 pk0, pk1;
            asm("v_cvt_pk_bf16_f32 %0, %1, %2" : "=v"(pk0) : "v"(p0), "v"(p1));
            asm("v_cvt_pk_bf16_f32 %0, %1, %2" : "=v"(pk1) : "v"(p2), "v"(p3));
            *(u32*)&Pw[r * 72 + 16 * tt + 4 * g] = pk0;
            *(u32*)&Pw[r * 72 + 16 * tt + 4 * g + 2] = pk1;
        }
        short8 pf0 = *(const short8*)&Pw[r * 72 + 8 * g];
        short8 pf1 = *(const short8*)&Pw[r * 72 + 32 + 8 * g];
#pragma unroll
        for (int dt = 0; dt < 4; dt++) {
            int row = 16 * dt + r;
            short8 vf0 = *(const short8*)&Vt[(size_t)(row * 8 + (g ^ sw)) * 8];
            short8 vf1 = *(const short8*)&Vt[(size_t)(row * 8 + ((4 + g) ^ sw)) * 8];
            ot[dt] = __builtin_amdgcn_mfma_f32_16x16x32_bf16(vf0, pf0, ot[dt], 0, 0, 0);
            ot[dt] = __builtin_amdgcn_mfma_f32_16x16x32_bf16(vf1, pf1, ot[dt], 0, 0, 0);
        }
        asm volatile("s_waitcnt lgkmcnt(0)" ::: "memory");
        __builtin_amdgcn_s_barrier();
        buf ^= 1;
    }

    float lrow = psA + psB;
    lrow += __shfl_xor(lrow, 16);
    lrow += __shfl_xor(lrow, 32);
    float inv = 1.f / lrow;
    u16* Op = attn_out + ((size_t)(b * 2048 + qbase + r)) * 1024 + h * 64;
#pragma unroll
    for (int dt = 0; dt < 4; dt++) {
        u16x4 o = { f2bf(ot[dt][0] * inv), f2bf(ot[dt][1] * inv),
                    f2bf(ot[dt][2] * inv), f2bf(ot[dt][3] * inv) };
        *(u16x4*)(Op + dt * 16 + 4 * g) = o;
    }
}

extern "C" void kernel_launch(void* const* d_in, const int* in_sizes, int n_in,
                              void* d_out, int out_size, void* d_ws, size_t ws_size,
                              hipStream_t stream) {
    const float* x = (const float*)d_in[0];
    const float* gamma = (const float*)d_in[1];
    const float* w_qkv = (const float*)d_in[2];
    const float* w_out = (const float*)d_in[3];
    const int* mods = (const int*)d_in[4];
    float* out = (float*)d_out;

    u16* ws = (u16*)d_ws;
    u16* xn    = ws;                 // 4096*2048
    u16* wqkvT = ws + 8388608;       // 3072*2048
    u16* woutT = ws + 14680064;      // 2048*1024
    u16* qb    = ws + 16777216;      // 2*16*2048*64
    u16* kb    = ws + 20971520;
    u16* vT    = ws + 25165824;
    u16* ao    = ws + 29360128;      // 4096*1024

    prep<<<dim3(12288), dim3(256), 0, stream>>>(x, gamma, w_qkv, w_out, xn, wqkvT, woutT);
    gemm32<0, 2, 4, 6><<<dim3(192), dim3(512), 0, stream>>>(xn, wqkvT, 4096, 3072, 2048,
                                                            nullptr, qb, kb, vT);
    flash_attn<<<dim3(16, 2, 32), dim3(256), 0, stream>>>(qb, kb, vT, mods, ao);
    gemm32<1, 4, 2, 8><<<dim3(256), dim3(512), 0, stream>>>(ao, woutT, 4096, 2048, 1024,
                                                            out, nullptr, nullptr, nullptr);
}